// Round 16
// baseline (698.284 us; speedup 1.0000x reference)
//
#include <hip/hip_runtime.h>
#include <hip/hip_bf16.h>
#include <math.h>

#define H_   224
#define W_   224
#define HWsz 50176      // 224*224
#define Cch  128

// Kernel A: out tile 8x8, halo 2 -> 12x12
#define TAH 8
#define TAW 8
#define HAH 12
#define HAW 12
#define NHALO_A (HAH*HAW)   // 144  (row 144 = dedicated zero pixel)

// Kernel B: patch 8 rows x 16 cols, halo 1 -> 10x18
#define PBH 8
#define PBW 16
#define HBH 10
#define HBW 18
#define NHALO_B (HBH*HBW)   // 180
#define GPITCH 136          // g_s row pitch in bf16 units (272 B)

// lnT: pixels per block
#define TPX 64

typedef __bf16 bf16x8 __attribute__((ext_vector_type(8)));
typedef float  f32x4  __attribute__((ext_vector_type(4)));

__device__ __forceinline__ float bf2f(__hip_bfloat16 v) { return __bfloat162float(v); }
__device__ __forceinline__ __hip_bfloat16 f2bf(float v) { return __float2bfloat16(v); }
__device__ __forceinline__ float ubf2f(unsigned short u) {
    unsigned x = ((unsigned)u) << 16; return __int_as_float((int)x);
}
__device__ __forceinline__ unsigned short f2ubf(float f) {
    __hip_bfloat16 h = __float2bfloat16(f);
    return *reinterpret_cast<unsigned short*>(&h);
}
// exact GELU (erf) — the fast tanh variant failed post-timing revalidation
// in rounds 14/15; keep the proven-deterministic path.
__device__ __forceinline__ float gelu_exact(float x) {
    return 0.5f * x * (1.0f + erff(x * 0.70710678118654752440f));
}
// readfirstlane a wave-uniform pointer into SGPRs so weight reads become s_loads
__device__ __forceinline__ const float* rflp(const float* p) {
    unsigned long long v = (unsigned long long)p;
    unsigned lo = __builtin_amdgcn_readfirstlane((unsigned)v);
    unsigned hi = __builtin_amdgcn_readfirstlane((unsigned)(v >> 32));
    return (const float*)(((unsigned long long)hi << 32) | lo);
}

// =====================================================================
// prep: transpose ldw depthwise weights to dwT[tap][c]
// =====================================================================
__global__ __launch_bounds__(256)
void prep(const float* __restrict__ ldww, float* __restrict__ dwT)
{
    const int i = blockIdx.x * 256 + threadIdx.x;
    if (i < 9 * Cch) {
        const int t = i >> 7, c = i & 127;
        dwT[i] = ldww[c * 9 + t];
    }
}

// =====================================================================
// lnT: LN1 (stats + normalize) + NCHW->NHWC transpose, bf16 out
// =====================================================================
__global__ __launch_bounds__(256, 4)
void lnT(const float* __restrict__ x,
         const float* __restrict__ n1w, const float* __restrict__ n1b,
         unsigned int* __restrict__ y)
{
    __shared__ float xs[TPX][Cch + 1];      // 33,024 B
    __shared__ float rs_[4][TPX], rss_[4][TPX];
    __shared__ float2 st_s[TPX];

    const int t   = threadIdx.x;
    const int b   = blockIdx.y;
    const int sp0 = blockIdx.x * TPX;

    // phase a: coalesced load, transpose into LDS
    {
        const int lane = t & 63, wv = t >> 6;
        const float* xb = x + (size_t)b * Cch * HWsz + sp0 + lane;
        #pragma unroll 8
        for (int k = 0; k < 32; ++k) {
            const int c = wv * 32 + k;
            xs[lane][c] = xb[(size_t)c * HWsz];
        }
    }
    __syncthreads();

    // phase b: per-pixel stats (4 threads per pixel)
    {
        const int p = t & 63, q = t >> 6;
        float s = 0.f, ss = 0.f;
        #pragma unroll
        for (int k = 0; k < 32; ++k) {
            const float v = xs[p][q * 32 + k];
            s += v; ss += v * v;
        }
        rs_[q][p] = s; rss_[q][p] = ss;
    }
    __syncthreads();
    if (t < TPX) {
        const float S  = rs_[0][t] + rs_[1][t] + rs_[2][t] + rs_[3][t];
        const float SS = rss_[0][t] + rss_[1][t] + rss_[2][t] + rss_[3][t];
        const float mu  = S * (1.0f / 128.0f);
        const float var = SS * (1.0f / 128.0f) - mu * mu;
        st_s[t] = make_float2(mu, rsqrtf(var + 1e-6f));
    }
    __syncthreads();

    // phase c: normalize + pack bf16 + coalesced NHWC store
    {
        const int ch = t & 15;          // 16B chunk (8 channels)
        const int pb = t >> 4;          // 0..15
        float w8[8], b8[8];
        #pragma unroll
        for (int j = 0; j < 8; ++j) {
            w8[j] = n1w[ch * 8 + j];
            b8[j] = n1b[ch * 8 + j];
        }
        #pragma unroll
        for (int it = 0; it < 4; ++it) {
            const int p = it * 16 + pb;
            const float2 st = st_s[p];
            unsigned int pk[4];
            #pragma unroll
            for (int u = 0; u < 4; ++u) {
                const int c0 = ch * 8 + u * 2;
                const float v0 = (xs[p][c0]     - st.x) * st.y * w8[u*2]   + b8[u*2];
                const float v1 = (xs[p][c0 + 1] - st.x) * st.y * w8[u*2+1] + b8[u*2+1];
                pk[u] = (unsigned int)f2ubf(v0) | ((unsigned int)f2ubf(v1) << 16);
            }
            *reinterpret_cast<uint4*>(y + ((size_t)b * HWsz + sp0 + p) * 64 + ch * 4) =
                make_uint4(pk[0], pk[1], pk[2], pk[3]);
        }
    }
}

// =====================================================================
// conv_taps: accumulate 9 taps x 32 channels from swizzled NHWC LDS.
// w9 MUST be an SGPR (readfirstlane'd) pointer -> weights are s_loads.
// mask handled by redirecting the tap address to the zero row (144)
// =====================================================================
__device__ __forceinline__ void conv_taps(
    float* __restrict__ G, const uint4* __restrict__ ys4,
    const float* __restrict__ w9,
    int rb, int cb, int chunkBase,
    const bool* rowOK, const bool* colOK, bool useMask)
{
    #pragma unroll
    for (int t3 = 0; t3 < 3; ++t3)
        #pragma unroll
        for (int t4 = 0; t4 < 3; ++t4) {
            const int tap = t3 * 3 + t4;
            int q = (rb + t3) * HAW + (cb + t4);
            if (useMask && !(rowOK[t3] && colOK[t4])) q = NHALO_A;  // zero row
            const char* base = reinterpret_cast<const char*>(ys4) + q * 256;
            const int sw = q & 15;
            #pragma unroll
            for (int u = 0; u < 4; ++u) {
                const uint4 t = *reinterpret_cast<const uint4*>(
                                    base + (((chunkBase + u) ^ sw) << 4));
                const int i0 = u * 8;
                G[i0+0] = fmaf(w9[(i0+0)*9+tap], ubf2f((unsigned short)(t.x & 0xffffu)), G[i0+0]);
                G[i0+1] = fmaf(w9[(i0+1)*9+tap], ubf2f((unsigned short)(t.x >> 16)),     G[i0+1]);
                G[i0+2] = fmaf(w9[(i0+2)*9+tap], ubf2f((unsigned short)(t.y & 0xffffu)), G[i0+2]);
                G[i0+3] = fmaf(w9[(i0+3)*9+tap], ubf2f((unsigned short)(t.y >> 16)),     G[i0+3]);
                G[i0+4] = fmaf(w9[(i0+4)*9+tap], ubf2f((unsigned short)(t.z & 0xffffu)), G[i0+4]);
                G[i0+5] = fmaf(w9[(i0+5)*9+tap], ubf2f((unsigned short)(t.z >> 16)),     G[i0+5]);
                G[i0+6] = fmaf(w9[(i0+6)*9+tap], ubf2f((unsigned short)(t.w & 0xffffu)), G[i0+6]);
                G[i0+7] = fmaf(w9[(i0+7)*9+tap], ubf2f((unsigned short)(t.w >> 16)),     G[i0+7]);
            }
        }
}

// =====================================================================
// Kernel A (8x8 tile, wave=chunk): y(NHWC bf16) -> 4 shift branches + c5
// -> zx LDS exchange (aliased onto dead y_s4) -> shuffle-pack -> z + LN2 stats
// =====================================================================
__global__ __launch_bounds__(256, 4)
void kernelA(const unsigned short* __restrict__ y,
             const float* __restrict__ c5w, const float* __restrict__ c5b,
             const float* __restrict__ s1dw, const float* __restrict__ s1db,
             const float* __restrict__ s1pw, const float* __restrict__ s1pb,
             const float* __restrict__ s2dw, const float* __restrict__ s2db,
             const float* __restrict__ s2pw, const float* __restrict__ s2pb,
             const float* __restrict__ s3dw, const float* __restrict__ s3db,
             const float* __restrict__ s3pw, const float* __restrict__ s3pb,
             const float* __restrict__ s4dw, const float* __restrict__ s4db,
             const float* __restrict__ s4pw, const float* __restrict__ s4pb,
             unsigned int* __restrict__ zout, float2* __restrict__ st2)
{
    __shared__ uint4 y_s4[(NHALO_A + 1) * 16];   // 37,120 B (incl zero row)
    uint4* zx4 = y_s4;                           // y_s4 dead before zx writes

    const int tid = threadIdx.x;
    const int b   = blockIdx.z;
    const int h0  = blockIdx.y * TAH;
    const int w0  = blockIdx.x * TAW;

    // ---------- Phase 1: coalesced NHWC load -> swizzled b128 LDS store ----------
    {
        const int ch = tid & 15;          // 16B chunk (8 channels)
        const int pb = tid >> 4;          // 0..15
        #pragma unroll
        for (int it = 0; it < 9; ++it) {
            const int p  = it * 16 + pb;  // halo pixel index 0..143
            const int ph = p / HAW, pw2 = p - ph * HAW;
            const int gy = h0 - 2 + ph, gx = w0 - 2 + pw2;
            uint4 v = make_uint4(0u, 0u, 0u, 0u);
            if ((unsigned)gy < (unsigned)H_ && (unsigned)gx < (unsigned)W_)
                v = *reinterpret_cast<const uint4*>(
                    y + ((size_t)b * HWsz + (size_t)gy * W_ + gx) * Cch + ch * 8);
            y_s4[p * 16 + (ch ^ pb)] = v;
        }
        if (tid < 16) y_s4[NHALO_A * 16 + tid] = make_uint4(0u, 0u, 0u, 0u);
    }
    __syncthreads();

    // ---------- Phase 2: wave k computes branch k for all 64 pixels ----------
    {
        const int px  = tid & 63;          // pixel in 8x8 tile
        const int k   = tid >> 6;          // chunk id, wave-uniform
        const int py  = px >> 3, pxx = px & 7;
        const int gh  = h0 + py, gw = w0 + pxx;

        bool rowOK[3], colOK[3];
        #pragma unroll
        for (int t = 0; t < 3; ++t) {
            rowOK[t] = (gh - 1 + t >= 0) && (gh - 1 + t < H_);
            colOK[t] = (gw - 1 + t >= 0) && (gw - 1 + t < W_);
        }

        // chunk table: k=0:s1 sh(1,1) ob 64 | k=1:s2 sh(-1,1) ob 0
        //              k=2:s3 sh(-1,-1) ob 96 | k=3:s4 sh(1,-1) ob 32
        const float* dwW = rflp(k == 0 ? s1dw : k == 1 ? s2dw : k == 2 ? s3dw : s4dw);
        const float* dwB = rflp(k == 0 ? s1db : k == 1 ? s2db : k == 2 ? s3db : s4db);
        const float* pwW = rflp(k == 0 ? s1pw : k == 1 ? s2pw : k == 2 ? s3pw : s4pw);
        const float* pwB = rflp(k == 0 ? s1pb : k == 1 ? s2pb : k == 2 ? s3pb : s4pb);
        const int shh = (k == 0 || k == 3) ? 1 : -1;
        const int shw = (k <= 1) ? 1 : -1;
        const int ob  = (k == 0) ? 64 : (k == 1) ? 0 : (k == 2) ? 96 : 32;
        const float* c5wk = rflp(c5w + ob * 9);
        const float* c5bk = rflp(c5b + ob);

        float G[32], OV[32];

        #pragma unroll
        for (int i = 0; i < 32; ++i) G[i] = dwB[i];
        conv_taps(G, y_s4, dwW, py + 1 - shh, pxx + 1 - shw, k * 4, rowOK, colOK, true);
        #pragma unroll
        for (int i = 0; i < 32; ++i) G[i] = gelu_exact(G[i]);

        #pragma unroll 4
        for (int j = 0; j < 32; ++j) {
            float a = pwB[j] + c5bk[j];
            #pragma unroll
            for (int i = 0; i < 32; ++i)
                a = fmaf(pwW[j * 32 + i], G[i], a);
            OV[j] = a;
        }

        conv_taps(OV, y_s4, c5wk, py + 1, pxx + 1, ob >> 3, rowOK, colOK, false);

        // y_s4 is now dead; zx aliases it — barrier before overwrite
        __syncthreads();

        // write OV (bf16) to zx exchange buffer, swizzled
        const int sw = px & 15;
        #pragma unroll
        for (int u = 0; u < 4; ++u) {
            uint4 o;
            o.x = (unsigned)f2ubf(OV[u*8+0]) | ((unsigned)f2ubf(OV[u*8+1]) << 16);
            o.y = (unsigned)f2ubf(OV[u*8+2]) | ((unsigned)f2ubf(OV[u*8+3]) << 16);
            o.z = (unsigned)f2ubf(OV[u*8+4]) | ((unsigned)f2ubf(OV[u*8+5]) << 16);
            o.w = (unsigned)f2ubf(OV[u*8+6]) | ((unsigned)f2ubf(OV[u*8+7]) << 16);
            zx4[px * 16 + ((k * 4 + u) ^ sw)] = o;
        }
    }
    __syncthreads();

    // ---------- Phase 3: shuffle-pack zx -> z global + LN2 stats ----------
    {
        const int ppx = tid >> 2;          // pixel 0..63
        const int s   = tid & 3;           // 32-channel segment of z
        const int klo = (s < 2) ? 1 : 3;   // lo source chunk
        const int khi = (s < 2) ? 0 : 2;   // hi source chunk
        const int cb  = (s & 1) * 2;       // uint4 offset within chunk
        const int sw  = ppx & 15;

        const uint4 lo0 = zx4[ppx * 16 + ((klo * 4 + cb)     ^ sw)];
        const uint4 lo1 = zx4[ppx * 16 + ((klo * 4 + cb + 1) ^ sw)];
        const uint4 hi0 = zx4[ppx * 16 + ((khi * 4 + cb)     ^ sw)];
        const uint4 hi1 = zx4[ppx * 16 + ((khi * 4 + cb + 1) ^ sw)];

        uint4 o0, o1, o2, o3;
        o0.x = (lo0.x & 0xffffu) | (hi0.x << 16);
        o0.y = (lo0.x >> 16)     | (hi0.x & 0xffff0000u);
        o0.z = (lo0.y & 0xffffu) | (hi0.y << 16);
        o0.w = (lo0.y >> 16)     | (hi0.y & 0xffff0000u);
        o1.x = (lo0.z & 0xffffu) | (hi0.z << 16);
        o1.y = (lo0.z >> 16)     | (hi0.z & 0xffff0000u);
        o1.z = (lo0.w & 0xffffu) | (hi0.w << 16);
        o1.w = (lo0.w >> 16)     | (hi0.w & 0xffff0000u);
        o2.x = (lo1.x & 0xffffu) | (hi1.x << 16);
        o2.y = (lo1.x >> 16)     | (hi1.x & 0xffff0000u);
        o2.z = (lo1.y & 0xffffu) | (hi1.y << 16);
        o2.w = (lo1.y >> 16)     | (hi1.y & 0xffff0000u);
        o3.x = (lo1.z & 0xffffu) | (hi1.z << 16);
        o3.y = (lo1.z >> 16)     | (hi1.z & 0xffff0000u);
        o3.z = (lo1.w & 0xffffu) | (hi1.w << 16);
        o3.w = (lo1.w >> 16)     | (hi1.w & 0xffff0000u);

        const int gh = h0 + (ppx >> 3), gw = w0 + (ppx & 7);
        unsigned int* zp = zout + ((size_t)b * HWsz + (size_t)gh * W_ + gw) * 64 + s * 16;
        *reinterpret_cast<uint4*>(zp + 0)  = o0;
        *reinterpret_cast<uint4*>(zp + 4)  = o1;
        *reinterpret_cast<uint4*>(zp + 8)  = o2;
        *reinterpret_cast<uint4*>(zp + 12) = o3;

        // stats over the 32 channels this thread packed
        float s1 = 0.f, s2 = 0.f;
        #define ACC(wrd) { const float fl = ubf2f((unsigned short)((wrd) & 0xffffu)); \
                           const float fh = ubf2f((unsigned short)((wrd) >> 16));     \
                           s1 += fl + fh; s2 += fl * fl + fh * fh; }
        ACC(o0.x) ACC(o0.y) ACC(o0.z) ACC(o0.w)
        ACC(o1.x) ACC(o1.y) ACC(o1.z) ACC(o1.w)
        ACC(o2.x) ACC(o2.y) ACC(o2.z) ACC(o2.w)
        ACC(o3.x) ACC(o3.y) ACC(o3.z) ACC(o3.w)
        #undef ACC

        s1 += __shfl_xor(s1, 1); s1 += __shfl_xor(s1, 2);
        s2 += __shfl_xor(s2, 1); s2 += __shfl_xor(s2, 2);
        if (s == 0) {
            const float mu  = s1 * (1.0f / 128.0f);
            const float var = s2 * (1.0f / 128.0f) - mu * mu;
            st2[(size_t)b * HWsz + (size_t)gh * W_ + gw] = make_float2(mu, rsqrtf(var + 1e-6f));
        }
    }
}

// =====================================================================
// Kernel B: stage LN2(z)-halo in LDS (bf16, swizzled NHWC) ->
//           dw3 + GELU from LDS -> g_s -> 128x128 pointwise via MFMA
// =====================================================================
__global__ __launch_bounds__(256, 2)
void kernelB(const unsigned short* __restrict__ z, const float2* __restrict__ st2,
             const float* __restrict__ n2w, const float* __restrict__ n2b,
             const float* __restrict__ dwT, const float* __restrict__ dwB,
             const float* __restrict__ pwW, const float* __restrict__ pwB,
             float* __restrict__ out)
{
    __shared__ uint4 w_s4[NHALO_B * 16];                 // 46,080 B
    __shared__ unsigned short g_s[PBH * PBW * GPITCH];   // 34,816 B

    const int tid  = threadIdx.x;
    const int lane = tid & 63;
    const int wv   = tid >> 6;
    const int b    = blockIdx.z;
    const int h0   = blockIdx.y * PBH;
    const int w0   = blockIdx.x * PBW;

    // ---------------- Phase S: stage LN2-normalized halo into w_s4 ----------------
    {
        const int ch = tid & 15;          // 16B chunk (8 channels)
        const int pb = tid >> 4;          // 0..15
        float nw[8], nb[8];
        #pragma unroll
        for (int j = 0; j < 8; ++j) {
            nw[j] = n2w[ch * 8 + j];
            nb[j] = n2b[ch * 8 + j];
        }
        #pragma unroll
        for (int it = 0; it < 12; ++it) {
            const int p = it * 16 + pb;   // halo pixel 0..179
            if (p < NHALO_B) {
                const int ph = p / HBW, pw2 = p - ph * HBW;
                const int gy = h0 - 1 + ph, gx = w0 - 1 + pw2;
                uint4 o = make_uint4(0u, 0u, 0u, 0u);
                if ((unsigned)gy < (unsigned)H_ && (unsigned)gx < (unsigned)W_) {
                    const size_t pp = (size_t)b * HWsz + (size_t)gy * W_ + gx;
                    const uint4 zv = *reinterpret_cast<const uint4*>(z + pp * Cch + ch * 8);
                    const float2 st = st2[pp];
                    const float f0 = (ubf2f((unsigned short)(zv.x & 0xffffu)) - st.x) * st.y * nw[0] + nb[0];
                    const float f1 = (ubf2f((unsigned short)(zv.x >> 16))     - st.x) * st.y * nw[1] + nb[1];
                    const float f2 = (ubf2f((unsigned short)(zv.y & 0xffffu)) - st.x) * st.y * nw[2] + nb[2];
                    const float f3 = (ubf2f((unsigned short)(zv.y >> 16))     - st.x) * st.y * nw[3] + nb[3];
                    const float f4 = (ubf2f((unsigned short)(zv.z & 0xffffu)) - st.x) * st.y * nw[4] + nb[4];
                    const float f5 = (ubf2f((unsigned short)(zv.z >> 16))     - st.x) * st.y * nw[5] + nb[5];
                    const float f6 = (ubf2f((unsigned short)(zv.w & 0xffffu)) - st.x) * st.y * nw[6] + nb[6];
                    const float f7 = (ubf2f((unsigned short)(zv.w >> 16))     - st.x) * st.y * nw[7] + nb[7];
                    o.x = (unsigned)f2ubf(f0) | ((unsigned)f2ubf(f1) << 16);
                    o.y = (unsigned)f2ubf(f2) | ((unsigned)f2ubf(f3) << 16);
                    o.z = (unsigned)f2ubf(f4) | ((unsigned)f2ubf(f5) << 16);
                    o.w = (unsigned)f2ubf(f6) | ((unsigned)f2ubf(f7) << 16);
                }
                w_s4[p * 16 + (ch ^ (p & 15))] = o;
            }
        }
    }
    __syncthreads();

    // ---------------- Phase L: dw3 + GELU from LDS -> g_s (bf16) ----------------
    {
        const int cc = lane & 15;          // channel chunk (8 ch)
        const int sl = lane >> 4;          // 0..3
        const int s  = wv * 4 + sl;        // col in patch 0..15
        const int cbase = cc * 8;

        float db[8];
        float wt[9][8];
        #pragma unroll
        for (int j = 0; j < 8; ++j) db[j] = dwB[cbase + j];
        #pragma unroll
        for (int t = 0; t < 9; ++t)
            #pragma unroll
            for (int j = 0; j < 8; ++j)
                wt[t][j] = dwT[t * Cch + cbase + j];

        for (int r = 0; r < PBH; ++r) {
            float a[8];
            #pragma unroll
            for (int j = 0; j < 8; ++j) a[j] = db[j];

            #pragma unroll
            for (int dy = 0; dy < 3; ++dy)
                #pragma unroll
                for (int dx = 0; dx < 3; ++dx) {
                    const int tap = dy * 3 + dx;
                    const int q = (r + dy) * HBW + (s + dx);
                    const uint4 t4 = w_s4[q * 16 + (cc ^ (q & 15))];
                    a[0] = fmaf(wt[tap][0], ubf2f((unsigned short)(t4.x & 0xffffu)), a[0]);
                    a[1] = fmaf(wt[tap][1], ubf2f((unsigned short)(t4.x >> 16)),     a[1]);
                    a[2] = fmaf(wt[tap][2], ubf2f((unsigned short)(t4.y & 0xffffu)), a[2]);
                    a[3] = fmaf(wt[tap][3], ubf2f((unsigned short)(t4.y >> 16)),     a[3]);
                    a[4] = fmaf(wt[tap][4], ubf2f((unsigned short)(t4.z & 0xffffu)), a[4]);
                    a[5] = fmaf(wt[tap][5], ubf2f((unsigned short)(t4.z >> 16)),     a[5]);
                    a[6] = fmaf(wt[tap][6], ubf2f((unsigned short)(t4.w & 0xffffu)), a[6]);
                    a[7] = fmaf(wt[tap][7], ubf2f((unsigned short)(t4.w >> 16)),     a[7]);
                }

            unsigned int pk[4];
            #pragma unroll
            for (int q = 0; q < 4; ++q) {
                const unsigned short lo = f2ubf(gelu_exact(a[2*q]));
                const unsigned short hi = f2ubf(gelu_exact(a[2*q+1]));
                pk[q] = (unsigned int)lo | ((unsigned int)hi << 16);
            }
            const int row = r * PBW + s;
            const int boff = row * (GPITCH * 2) + ((cbase * 2) ^ ((row & 3) << 4));
            *reinterpret_cast<uint4*>(reinterpret_cast<char*>(g_s) + boff) =
                make_uint4(pk[0], pk[1], pk[2], pk[3]);
        }
    }
    __syncthreads();

    // ---------------- Phase P: 128x128 pointwise via MFMA ----------------
    {
        const int ll = lane & 15;
        const int lh = lane >> 4;

        bf16x8 bfr[2][4];
        float  pb[2];
        #pragma unroll
        for (int t2 = 0; t2 < 2; ++t2) {
            const int o = (wv * 2 + t2) * 16 + ll;
            pb[t2] = pwB[o];
            #pragma unroll
            for (int kt = 0; kt < 4; ++kt) {
                const float* wp = pwW + (size_t)o * Cch + kt * 32 + lh * 8;
                bf16x8 vv;
                #pragma unroll
                for (int j = 0; j < 8; ++j) vv[j] = (__bf16)wp[j];
                bfr[t2][kt] = vv;
            }
        }

        #pragma unroll
        for (int r = 0; r < PBH; ++r) {
            const int row = r * PBW + ll;
            bf16x8 af[4];
            #pragma unroll
            for (int kt = 0; kt < 4; ++kt) {
                const int boff = row * (GPITCH * 2) + ((kt * 64 + lh * 16) ^ ((row & 3) << 4));
                af[kt] = *reinterpret_cast<const bf16x8*>(
                            reinterpret_cast<const char*>(g_s) + boff);
            }
            #pragma unroll
            for (int t2 = 0; t2 < 2; ++t2) {
                f32x4 acc = {0.f, 0.f, 0.f, 0.f};
                #pragma unroll
                for (int kt = 0; kt < 4; ++kt)
                    acc = __builtin_amdgcn_mfma_f32_16x16x32_bf16(af[kt], bfr[t2][kt], acc, 0, 0, 0);
                const int o = (wv * 2 + t2) * 16 + ll;
                float4 res = make_float4(acc[0] + pb[t2], acc[1] + pb[t2],
                                         acc[2] + pb[t2], acc[3] + pb[t2]);
                *reinterpret_cast<float4*>(
                    out + ((size_t)b * Cch + o) * HWsz + (size_t)(h0 + r) * W_ + w0 + lh * 4) = res;
            }
        }
    }
}

// =====================================================================
extern "C" void kernel_launch(void* const* d_in, const int* in_sizes, int n_in,
                              void* d_out, int out_size, void* d_ws, size_t ws_size,
                              hipStream_t stream)
{
    const float* x    = (const float*)d_in[0];
    const float* n1w  = (const float*)d_in[1];
    const float* n1b  = (const float*)d_in[2];
    const float* n2w  = (const float*)d_in[3];
    const float* n2b  = (const float*)d_in[4];
    const float* c5w  = (const float*)d_in[5];
    const float* c5b  = (const float*)d_in[6];
    const float* ldww = (const float*)d_in[7];
    const float* ldwb = (const float*)d_in[8];
    const float* lpww = (const float*)d_in[9];
    const float* lpwb = (const float*)d_in[10];
    const float* s1dw = (const float*)d_in[11];
    const float* s1db = (const float*)d_in[12];
    const float* s1pw = (const float*)d_in[13];
    const float* s1pb = (const float*)d_in[14];
    const float* s2dw = (const float*)d_in[15];
    const float* s2db = (const float*)d_in[16];
    const float* s2pw = (const float*)d_in[17];
    const float* s2pb = (const float*)d_in[18];
    const float* s3dw = (const float*)d_in[19];
    const float* s3db = (const float*)d_in[20];
    const float* s3pw = (const float*)d_in[21];
    const float* s3pb = (const float*)d_in[22];
    const float* s4dw = (const float*)d_in[23];
    const float* s4db = (const float*)d_in[24];
    const float* s4pw = (const float*)d_in[25];
    const float* s4pb = (const float*)d_in[26];

    // workspace layout: y (bf16 NHWC) | z (bf16 NHWC) | st2 (float2) | dwT
    const size_t yBytes  = (size_t)8 * Cch * HWsz * sizeof(unsigned short); // 102,760,448
    const size_t zBytes  = yBytes;                                          // 102,760,448
    const size_t stBytes = (size_t)8 * HWsz * sizeof(float2);               //   3,211,264
    unsigned int*   y_u32 = (unsigned int*)d_ws;
    unsigned short* y_u16 = (unsigned short*)d_ws;
    unsigned int*   z_u32 = (unsigned int*)((char*)d_ws + yBytes);
    unsigned short* z_u16 = (unsigned short*)((char*)d_ws + yBytes);
    float2* st2 = (float2*)((char*)d_ws + yBytes + zBytes);
    float*  dwT = (float*)((char*)d_ws + yBytes + zBytes + stBytes);

    prep<<<dim3(5), 256, 0, stream>>>(ldww, dwT);
    lnT<<<dim3(HWsz / TPX, 8), 256, 0, stream>>>(x, n1w, n1b, y_u32);

    kernelA<<<dim3(W_ / TAW, H_ / TAH, 8), 256, 0, stream>>>(
        y_u16, c5w, c5b,
        s1dw, s1db, s1pw, s1pb,
        s2dw, s2db, s2pw, s2pb,
        s3dw, s3db, s3pw, s3pb,
        s4dw, s4db, s4pw, s4pb, z_u32, st2);

    kernelB<<<dim3(W_ / PBW, H_ / PBH, 8), 256, 0, stream>>>(
        z_u16, st2, n2w, n2b, dwT, ldwb, lpww, lpwb, (float*)d_out);
}

// Round 17
// 493.698 us; speedup vs baseline: 1.4144x; 1.4144x over previous
//
#include <hip/hip_runtime.h>
#include <hip/hip_bf16.h>
#include <math.h>

#define H_   224
#define W_   224
#define HWsz 50176      // 224*224
#define Cch  128

// Kernel A: out tile 8x8, halo 2 -> 12x12
#define TAH 8
#define TAW 8
#define HAH 12
#define HAW 12
#define NHALO_A (HAH*HAW)   // 144  (row 144 = dedicated zero pixel)

// Kernel B: patch 8 rows x 16 cols, halo 1 -> 10x18
#define PBH 8
#define PBW 16
#define HBH 10
#define HBW 18
#define NHALO_B (HBH*HBW)   // 180
#define GPITCH 136          // g_s row pitch in bf16 units (272 B)

// lnT: pixels per block
#define TPX 64

typedef __bf16 bf16x8 __attribute__((ext_vector_type(8)));
typedef float  f32x4  __attribute__((ext_vector_type(4)));

__device__ __forceinline__ float bf2f(__hip_bfloat16 v) { return __bfloat162float(v); }
__device__ __forceinline__ __hip_bfloat16 f2bf(float v) { return __float2bfloat16(v); }
__device__ __forceinline__ float ubf2f(unsigned short u) {
    unsigned x = ((unsigned)u) << 16; return __int_as_float((int)x);
}
__device__ __forceinline__ unsigned short f2ubf(float f) {
    __hip_bfloat16 h = __float2bfloat16(f);
    return *reinterpret_cast<unsigned short*>(&h);
}
// exact GELU (erf) — the fast tanh variant failed post-timing revalidation
// in rounds 14/15; keep the proven-deterministic path.
__device__ __forceinline__ float gelu_exact(float x) {
    return 0.5f * x * (1.0f + erff(x * 0.70710678118654752440f));
}
// readfirstlane a wave-uniform pointer into SGPRs so weight reads become s_loads
__device__ __forceinline__ const float* rflp(const float* p) {
    unsigned long long v = (unsigned long long)p;
    unsigned lo = __builtin_amdgcn_readfirstlane((unsigned)v);
    unsigned hi = __builtin_amdgcn_readfirstlane((unsigned)(v >> 32));
    return (const float*)(((unsigned long long)hi << 32) | lo);
}

// =====================================================================
// prep: transpose ldw depthwise weights to dwT[tap][c]
// =====================================================================
__global__ __launch_bounds__(256)
void prep(const float* __restrict__ ldww, float* __restrict__ dwT)
{
    const int i = blockIdx.x * 256 + threadIdx.x;
    if (i < 9 * Cch) {
        const int t = i >> 7, c = i & 127;
        dwT[i] = ldww[c * 9 + t];
    }
}

// =====================================================================
// lnT: LN1 (stats + normalize) + NCHW->NHWC transpose, bf16 out
// =====================================================================
__global__ __launch_bounds__(256, 4)
void lnT(const float* __restrict__ x,
         const float* __restrict__ n1w, const float* __restrict__ n1b,
         unsigned int* __restrict__ y)
{
    __shared__ float xs[TPX][Cch + 1];      // 33,024 B
    __shared__ float rs_[4][TPX], rss_[4][TPX];
    __shared__ float2 st_s[TPX];

    const int t   = threadIdx.x;
    const int b   = blockIdx.y;
    const int sp0 = blockIdx.x * TPX;

    // phase a: coalesced load, transpose into LDS
    {
        const int lane = t & 63, wv = t >> 6;
        const float* xb = x + (size_t)b * Cch * HWsz + sp0 + lane;
        #pragma unroll 8
        for (int k = 0; k < 32; ++k) {
            const int c = wv * 32 + k;
            xs[lane][c] = xb[(size_t)c * HWsz];
        }
    }
    __syncthreads();

    // phase b: per-pixel stats (4 threads per pixel)
    {
        const int p = t & 63, q = t >> 6;
        float s = 0.f, ss = 0.f;
        #pragma unroll
        for (int k = 0; k < 32; ++k) {
            const float v = xs[p][q * 32 + k];
            s += v; ss += v * v;
        }
        rs_[q][p] = s; rss_[q][p] = ss;
    }
    __syncthreads();
    if (t < TPX) {
        const float S  = rs_[0][t] + rs_[1][t] + rs_[2][t] + rs_[3][t];
        const float SS = rss_[0][t] + rss_[1][t] + rss_[2][t] + rss_[3][t];
        const float mu  = S * (1.0f / 128.0f);
        const float var = SS * (1.0f / 128.0f) - mu * mu;
        st_s[t] = make_float2(mu, rsqrtf(var + 1e-6f));
    }
    __syncthreads();

    // phase c: normalize + pack bf16 + coalesced NHWC store
    {
        const int ch = t & 15;          // 16B chunk (8 channels)
        const int pb = t >> 4;          // 0..15
        float w8[8], b8[8];
        #pragma unroll
        for (int j = 0; j < 8; ++j) {
            w8[j] = n1w[ch * 8 + j];
            b8[j] = n1b[ch * 8 + j];
        }
        #pragma unroll
        for (int it = 0; it < 4; ++it) {
            const int p = it * 16 + pb;
            const float2 st = st_s[p];
            unsigned int pk[4];
            #pragma unroll
            for (int u = 0; u < 4; ++u) {
                const int c0 = ch * 8 + u * 2;
                const float v0 = (xs[p][c0]     - st.x) * st.y * w8[u*2]   + b8[u*2];
                const float v1 = (xs[p][c0 + 1] - st.x) * st.y * w8[u*2+1] + b8[u*2+1];
                pk[u] = (unsigned int)f2ubf(v0) | ((unsigned int)f2ubf(v1) << 16);
            }
            *reinterpret_cast<uint4*>(y + ((size_t)b * HWsz + sp0 + p) * 64 + ch * 4) =
                make_uint4(pk[0], pk[1], pk[2], pk[3]);
        }
    }
}

// =====================================================================
// conv_taps: accumulate 9 taps x 32 channels from swizzled NHWC LDS.
// w9 MUST be an SGPR (readfirstlane'd) pointer -> weights are s_loads.
// mask handled by redirecting the tap address to the zero row (144)
// =====================================================================
__device__ __forceinline__ void conv_taps(
    float* __restrict__ G, const uint4* __restrict__ ys4,
    const float* __restrict__ w9,
    int rb, int cb, int chunkBase,
    const bool* rowOK, const bool* colOK, bool useMask)
{
    #pragma unroll
    for (int t3 = 0; t3 < 3; ++t3)
        #pragma unroll
        for (int t4 = 0; t4 < 3; ++t4) {
            const int tap = t3 * 3 + t4;
            int q = (rb + t3) * HAW + (cb + t4);
            if (useMask && !(rowOK[t3] && colOK[t4])) q = NHALO_A;  // zero row
            const char* base = reinterpret_cast<const char*>(ys4) + q * 256;
            const int sw = q & 15;
            #pragma unroll
            for (int u = 0; u < 4; ++u) {
                const uint4 t = *reinterpret_cast<const uint4*>(
                                    base + (((chunkBase + u) ^ sw) << 4));
                const int i0 = u * 8;
                G[i0+0] = fmaf(w9[(i0+0)*9+tap], ubf2f((unsigned short)(t.x & 0xffffu)), G[i0+0]);
                G[i0+1] = fmaf(w9[(i0+1)*9+tap], ubf2f((unsigned short)(t.x >> 16)),     G[i0+1]);
                G[i0+2] = fmaf(w9[(i0+2)*9+tap], ubf2f((unsigned short)(t.y & 0xffffu)), G[i0+2]);
                G[i0+3] = fmaf(w9[(i0+3)*9+tap], ubf2f((unsigned short)(t.y >> 16)),     G[i0+3]);
                G[i0+4] = fmaf(w9[(i0+4)*9+tap], ubf2f((unsigned short)(t.z & 0xffffu)), G[i0+4]);
                G[i0+5] = fmaf(w9[(i0+5)*9+tap], ubf2f((unsigned short)(t.z >> 16)),     G[i0+5]);
                G[i0+6] = fmaf(w9[(i0+6)*9+tap], ubf2f((unsigned short)(t.w & 0xffffu)), G[i0+6]);
                G[i0+7] = fmaf(w9[(i0+7)*9+tap], ubf2f((unsigned short)(t.w >> 16)),     G[i0+7]);
            }
        }
}

// =====================================================================
// Kernel A (8x8 tile, wave=chunk): y(NHWC bf16) -> 4 shift branches + c5
// -> zx LDS exchange (aliased onto dead y_s4) -> shuffle-pack -> z + LN2 stats
// =====================================================================
__global__ __launch_bounds__(256, 3)
void kernelA(const unsigned short* __restrict__ y,
             const float* __restrict__ c5w, const float* __restrict__ c5b,
             const float* __restrict__ s1dw, const float* __restrict__ s1db,
             const float* __restrict__ s1pw, const float* __restrict__ s1pb,
             const float* __restrict__ s2dw, const float* __restrict__ s2db,
             const float* __restrict__ s2pw, const float* __restrict__ s2pb,
             const float* __restrict__ s3dw, const float* __restrict__ s3db,
             const float* __restrict__ s3pw, const float* __restrict__ s3pb,
             const float* __restrict__ s4dw, const float* __restrict__ s4db,
             const float* __restrict__ s4pw, const float* __restrict__ s4pb,
             unsigned int* __restrict__ zout, float2* __restrict__ st2)
{
    __shared__ uint4 y_s4[(NHALO_A + 1) * 16];   // 37,120 B (incl zero row)
    uint4* zx4 = y_s4;                           // y_s4 dead before zx writes

    const int tid = threadIdx.x;
    const int b   = blockIdx.z;
    const int h0  = blockIdx.y * TAH;
    const int w0  = blockIdx.x * TAW;

    // ---------- Phase 1: coalesced NHWC load -> swizzled b128 LDS store ----------
    {
        const int ch = tid & 15;          // 16B chunk (8 channels)
        const int pb = tid >> 4;          // 0..15
        #pragma unroll
        for (int it = 0; it < 9; ++it) {
            const int p  = it * 16 + pb;  // halo pixel index 0..143
            const int ph = p / HAW, pw2 = p - ph * HAW;
            const int gy = h0 - 2 + ph, gx = w0 - 2 + pw2;
            uint4 v = make_uint4(0u, 0u, 0u, 0u);
            if ((unsigned)gy < (unsigned)H_ && (unsigned)gx < (unsigned)W_)
                v = *reinterpret_cast<const uint4*>(
                    y + ((size_t)b * HWsz + (size_t)gy * W_ + gx) * Cch + ch * 8);
            y_s4[p * 16 + (ch ^ pb)] = v;
        }
        if (tid < 16) y_s4[NHALO_A * 16 + tid] = make_uint4(0u, 0u, 0u, 0u);
    }
    __syncthreads();

    // ---------- Phase 2: wave k computes branch k for all 64 pixels ----------
    {
        const int px  = tid & 63;          // pixel in 8x8 tile
        const int k   = tid >> 6;          // chunk id, wave-uniform
        const int py  = px >> 3, pxx = px & 7;
        const int gh  = h0 + py, gw = w0 + pxx;

        bool rowOK[3], colOK[3];
        #pragma unroll
        for (int t = 0; t < 3; ++t) {
            rowOK[t] = (gh - 1 + t >= 0) && (gh - 1 + t < H_);
            colOK[t] = (gw - 1 + t >= 0) && (gw - 1 + t < W_);
        }

        // chunk table: k=0:s1 sh(1,1) ob 64 | k=1:s2 sh(-1,1) ob 0
        //              k=2:s3 sh(-1,-1) ob 96 | k=3:s4 sh(1,-1) ob 32
        const float* dwW = rflp(k == 0 ? s1dw : k == 1 ? s2dw : k == 2 ? s3dw : s4dw);
        const float* dwB = rflp(k == 0 ? s1db : k == 1 ? s2db : k == 2 ? s3db : s4db);
        const float* pwW = rflp(k == 0 ? s1pw : k == 1 ? s2pw : k == 2 ? s3pw : s4pw);
        const float* pwB = rflp(k == 0 ? s1pb : k == 1 ? s2pb : k == 2 ? s3pb : s4pb);
        const int shh = (k == 0 || k == 3) ? 1 : -1;
        const int shw = (k <= 1) ? 1 : -1;
        const int ob  = (k == 0) ? 64 : (k == 1) ? 0 : (k == 2) ? 96 : 32;
        const float* c5wk = rflp(c5w + ob * 9);
        const float* c5bk = rflp(c5b + ob);

        float G[32], OV[32];

        #pragma unroll
        for (int i = 0; i < 32; ++i) G[i] = dwB[i];
        conv_taps(G, y_s4, dwW, py + 1 - shh, pxx + 1 - shw, k * 4, rowOK, colOK, true);
        #pragma unroll
        for (int i = 0; i < 32; ++i) G[i] = gelu_exact(G[i]);

        #pragma unroll 4
        for (int j = 0; j < 32; ++j) {
            float a = pwB[j] + c5bk[j];
            #pragma unroll
            for (int i = 0; i < 32; ++i)
                a = fmaf(pwW[j * 32 + i], G[i], a);
            OV[j] = a;
        }

        conv_taps(OV, y_s4, c5wk, py + 1, pxx + 1, ob >> 3, rowOK, colOK, false);

        // y_s4 is now dead; zx aliases it — barrier before overwrite
        __syncthreads();

        // write OV (bf16) to zx exchange buffer, swizzled
        const int sw = px & 15;
        #pragma unroll
        for (int u = 0; u < 4; ++u) {
            uint4 o;
            o.x = (unsigned)f2ubf(OV[u*8+0]) | ((unsigned)f2ubf(OV[u*8+1]) << 16);
            o.y = (unsigned)f2ubf(OV[u*8+2]) | ((unsigned)f2ubf(OV[u*8+3]) << 16);
            o.z = (unsigned)f2ubf(OV[u*8+4]) | ((unsigned)f2ubf(OV[u*8+5]) << 16);
            o.w = (unsigned)f2ubf(OV[u*8+6]) | ((unsigned)f2ubf(OV[u*8+7]) << 16);
            zx4[px * 16 + ((k * 4 + u) ^ sw)] = o;
        }
    }
    __syncthreads();

    // ---------- Phase 3: shuffle-pack zx -> z global + LN2 stats ----------
    {
        const int ppx = tid >> 2;          // pixel 0..63
        const int s   = tid & 3;           // 32-channel segment of z
        const int klo = (s < 2) ? 1 : 3;   // lo source chunk
        const int khi = (s < 2) ? 0 : 2;   // hi source chunk
        const int cb  = (s & 1) * 2;       // uint4 offset within chunk
        const int sw  = ppx & 15;

        const uint4 lo0 = zx4[ppx * 16 + ((klo * 4 + cb)     ^ sw)];
        const uint4 lo1 = zx4[ppx * 16 + ((klo * 4 + cb + 1) ^ sw)];
        const uint4 hi0 = zx4[ppx * 16 + ((khi * 4 + cb)     ^ sw)];
        const uint4 hi1 = zx4[ppx * 16 + ((khi * 4 + cb + 1) ^ sw)];

        uint4 o0, o1, o2, o3;
        o0.x = (lo0.x & 0xffffu) | (hi0.x << 16);
        o0.y = (lo0.x >> 16)     | (hi0.x & 0xffff0000u);
        o0.z = (lo0.y & 0xffffu) | (hi0.y << 16);
        o0.w = (lo0.y >> 16)     | (hi0.y & 0xffff0000u);
        o1.x = (lo0.z & 0xffffu) | (hi0.z << 16);
        o1.y = (lo0.z >> 16)     | (hi0.z & 0xffff0000u);
        o1.z = (lo0.w & 0xffffu) | (hi0.w << 16);
        o1.w = (lo0.w >> 16)     | (hi0.w & 0xffff0000u);
        o2.x = (lo1.x & 0xffffu) | (hi1.x << 16);
        o2.y = (lo1.x >> 16)     | (hi1.x & 0xffff0000u);
        o2.z = (lo1.y & 0xffffu) | (hi1.y << 16);
        o2.w = (lo1.y >> 16)     | (hi1.y & 0xffff0000u);
        o3.x = (lo1.z & 0xffffu) | (hi1.z << 16);
        o3.y = (lo1.z >> 16)     | (hi1.z & 0xffff0000u);
        o3.z = (lo1.w & 0xffffu) | (hi1.w << 16);
        o3.w = (lo1.w >> 16)     | (hi1.w & 0xffff0000u);

        const int gh = h0 + (ppx >> 3), gw = w0 + (ppx & 7);
        unsigned int* zp = zout + ((size_t)b * HWsz + (size_t)gh * W_ + gw) * 64 + s * 16;
        *reinterpret_cast<uint4*>(zp + 0)  = o0;
        *reinterpret_cast<uint4*>(zp + 4)  = o1;
        *reinterpret_cast<uint4*>(zp + 8)  = o2;
        *reinterpret_cast<uint4*>(zp + 12) = o3;

        // stats over the 32 channels this thread packed
        float s1 = 0.f, s2 = 0.f;
        #define ACC(wrd) { const float fl = ubf2f((unsigned short)((wrd) & 0xffffu)); \
                           const float fh = ubf2f((unsigned short)((wrd) >> 16));     \
                           s1 += fl + fh; s2 += fl * fl + fh * fh; }
        ACC(o0.x) ACC(o0.y) ACC(o0.z) ACC(o0.w)
        ACC(o1.x) ACC(o1.y) ACC(o1.z) ACC(o1.w)
        ACC(o2.x) ACC(o2.y) ACC(o2.z) ACC(o2.w)
        ACC(o3.x) ACC(o3.y) ACC(o3.z) ACC(o3.w)
        #undef ACC

        s1 += __shfl_xor(s1, 1); s1 += __shfl_xor(s1, 2);
        s2 += __shfl_xor(s2, 1); s2 += __shfl_xor(s2, 2);
        if (s == 0) {
            const float mu  = s1 * (1.0f / 128.0f);
            const float var = s2 * (1.0f / 128.0f) - mu * mu;
            st2[(size_t)b * HWsz + (size_t)gh * W_ + gw] = make_float2(mu, rsqrtf(var + 1e-6f));
        }
    }
}

// =====================================================================
// Kernel B: stage LN2(z)-halo in LDS (bf16, swizzled NHWC) ->
//           dw3 + GELU from LDS -> g_s -> 128x128 pointwise via MFMA
// =====================================================================
__global__ __launch_bounds__(256, 2)
void kernelB(const unsigned short* __restrict__ z, const float2* __restrict__ st2,
             const float* __restrict__ n2w, const float* __restrict__ n2b,
             const float* __restrict__ dwT, const float* __restrict__ dwB,
             const float* __restrict__ pwW, const float* __restrict__ pwB,
             float* __restrict__ out)
{
    __shared__ uint4 w_s4[NHALO_B * 16];                 // 46,080 B
    __shared__ unsigned short g_s[PBH * PBW * GPITCH];   // 34,816 B

    const int tid  = threadIdx.x;
    const int lane = tid & 63;
    const int wv   = tid >> 6;
    const int b    = blockIdx.z;
    const int h0   = blockIdx.y * PBH;
    const int w0   = blockIdx.x * PBW;

    // ---------------- Phase S: stage LN2-normalized halo into w_s4 ----------------
    {
        const int ch = tid & 15;          // 16B chunk (8 channels)
        const int pb = tid >> 4;          // 0..15
        float nw[8], nb[8];
        #pragma unroll
        for (int j = 0; j < 8; ++j) {
            nw[j] = n2w[ch * 8 + j];
            nb[j] = n2b[ch * 8 + j];
        }
        #pragma unroll
        for (int it = 0; it < 12; ++it) {
            const int p = it * 16 + pb;   // halo pixel 0..179
            if (p < NHALO_B) {
                const int ph = p / HBW, pw2 = p - ph * HBW;
                const int gy = h0 - 1 + ph, gx = w0 - 1 + pw2;
                uint4 o = make_uint4(0u, 0u, 0u, 0u);
                if ((unsigned)gy < (unsigned)H_ && (unsigned)gx < (unsigned)W_) {
                    const size_t pp = (size_t)b * HWsz + (size_t)gy * W_ + gx;
                    const uint4 zv = *reinterpret_cast<const uint4*>(z + pp * Cch + ch * 8);
                    const float2 st = st2[pp];
                    const float f0 = (ubf2f((unsigned short)(zv.x & 0xffffu)) - st.x) * st.y * nw[0] + nb[0];
                    const float f1 = (ubf2f((unsigned short)(zv.x >> 16))     - st.x) * st.y * nw[1] + nb[1];
                    const float f2 = (ubf2f((unsigned short)(zv.y & 0xffffu)) - st.x) * st.y * nw[2] + nb[2];
                    const float f3 = (ubf2f((unsigned short)(zv.y >> 16))     - st.x) * st.y * nw[3] + nb[3];
                    const float f4 = (ubf2f((unsigned short)(zv.z & 0xffffu)) - st.x) * st.y * nw[4] + nb[4];
                    const float f5 = (ubf2f((unsigned short)(zv.z >> 16))     - st.x) * st.y * nw[5] + nb[5];
                    const float f6 = (ubf2f((unsigned short)(zv.w & 0xffffu)) - st.x) * st.y * nw[6] + nb[6];
                    const float f7 = (ubf2f((unsigned short)(zv.w >> 16))     - st.x) * st.y * nw[7] + nb[7];
                    o.x = (unsigned)f2ubf(f0) | ((unsigned)f2ubf(f1) << 16);
                    o.y = (unsigned)f2ubf(f2) | ((unsigned)f2ubf(f3) << 16);
                    o.z = (unsigned)f2ubf(f4) | ((unsigned)f2ubf(f5) << 16);
                    o.w = (unsigned)f2ubf(f6) | ((unsigned)f2ubf(f7) << 16);
                }
                w_s4[p * 16 + (ch ^ (p & 15))] = o;
            }
        }
    }
    __syncthreads();

    // ---------------- Phase L: dw3 + GELU from LDS -> g_s (bf16) ----------------
    {
        const int cc = lane & 15;          // channel chunk (8 ch)
        const int sl = lane >> 4;          // 0..3
        const int s  = wv * 4 + sl;        // col in patch 0..15
        const int cbase = cc * 8;

        float db[8];
        float wt[9][8];
        #pragma unroll
        for (int j = 0; j < 8; ++j) db[j] = dwB[cbase + j];
        #pragma unroll
        for (int t = 0; t < 9; ++t)
            #pragma unroll
            for (int j = 0; j < 8; ++j)
                wt[t][j] = dwT[t * Cch + cbase + j];

        for (int r = 0; r < PBH; ++r) {
            float a[8];
            #pragma unroll
            for (int j = 0; j < 8; ++j) a[j] = db[j];

            #pragma unroll
            for (int dy = 0; dy < 3; ++dy)
                #pragma unroll
                for (int dx = 0; dx < 3; ++dx) {
                    const int tap = dy * 3 + dx;
                    const int q = (r + dy) * HBW + (s + dx);
                    const uint4 t4 = w_s4[q * 16 + (cc ^ (q & 15))];
                    a[0] = fmaf(wt[tap][0], ubf2f((unsigned short)(t4.x & 0xffffu)), a[0]);
                    a[1] = fmaf(wt[tap][1], ubf2f((unsigned short)(t4.x >> 16)),     a[1]);
                    a[2] = fmaf(wt[tap][2], ubf2f((unsigned short)(t4.y & 0xffffu)), a[2]);
                    a[3] = fmaf(wt[tap][3], ubf2f((unsigned short)(t4.y >> 16)),     a[3]);
                    a[4] = fmaf(wt[tap][4], ubf2f((unsigned short)(t4.z & 0xffffu)), a[4]);
                    a[5] = fmaf(wt[tap][5], ubf2f((unsigned short)(t4.z >> 16)),     a[5]);
                    a[6] = fmaf(wt[tap][6], ubf2f((unsigned short)(t4.w & 0xffffu)), a[6]);
                    a[7] = fmaf(wt[tap][7], ubf2f((unsigned short)(t4.w >> 16)),     a[7]);
                }

            unsigned int pk[4];
            #pragma unroll
            for (int q = 0; q < 4; ++q) {
                const unsigned short lo = f2ubf(gelu_exact(a[2*q]));
                const unsigned short hi = f2ubf(gelu_exact(a[2*q+1]));
                pk[q] = (unsigned int)lo | ((unsigned int)hi << 16);
            }
            const int row = r * PBW + s;
            const int boff = row * (GPITCH * 2) + ((cbase * 2) ^ ((row & 3) << 4));
            *reinterpret_cast<uint4*>(reinterpret_cast<char*>(g_s) + boff) =
                make_uint4(pk[0], pk[1], pk[2], pk[3]);
        }
    }
    __syncthreads();

    // ---------------- Phase P: 128x128 pointwise via MFMA ----------------
    {
        const int ll = lane & 15;
        const int lh = lane >> 4;

        bf16x8 bfr[2][4];
        float  pb[2];
        #pragma unroll
        for (int t2 = 0; t2 < 2; ++t2) {
            const int o = (wv * 2 + t2) * 16 + ll;
            pb[t2] = pwB[o];
            #pragma unroll
            for (int kt = 0; kt < 4; ++kt) {
                const float* wp = pwW + (size_t)o * Cch + kt * 32 + lh * 8;
                bf16x8 vv;
                #pragma unroll
                for (int j = 0; j < 8; ++j) vv[j] = (__bf16)wp[j];
                bfr[t2][kt] = vv;
            }
        }

        #pragma unroll
        for (int r = 0; r < PBH; ++r) {
            const int row = r * PBW + ll;
            bf16x8 af[4];
            #pragma unroll
            for (int kt = 0; kt < 4; ++kt) {
                const int boff = row * (GPITCH * 2) + ((kt * 64 + lh * 16) ^ ((row & 3) << 4));
                af[kt] = *reinterpret_cast<const bf16x8*>(
                            reinterpret_cast<const char*>(g_s) + boff);
            }
            #pragma unroll
            for (int t2 = 0; t2 < 2; ++t2) {
                f32x4 acc = {0.f, 0.f, 0.f, 0.f};
                #pragma unroll
                for (int kt = 0; kt < 4; ++kt)
                    acc = __builtin_amdgcn_mfma_f32_16x16x32_bf16(af[kt], bfr[t2][kt], acc, 0, 0, 0);
                const int o = (wv * 2 + t2) * 16 + ll;
                float4 res = make_float4(acc[0] + pb[t2], acc[1] + pb[t2],
                                         acc[2] + pb[t2], acc[3] + pb[t2]);
                *reinterpret_cast<float4*>(
                    out + ((size_t)b * Cch + o) * HWsz + (size_t)(h0 + r) * W_ + w0 + lh * 4) = res;
            }
        }
    }
}

// =====================================================================
extern "C" void kernel_launch(void* const* d_in, const int* in_sizes, int n_in,
                              void* d_out, int out_size, void* d_ws, size_t ws_size,
                              hipStream_t stream)
{
    const float* x    = (const float*)d_in[0];
    const float* n1w  = (const float*)d_in[1];
    const float* n1b  = (const float*)d_in[2];
    const float* n2w  = (const float*)d_in[3];
    const float* n2b  = (const float*)d_in[4];
    const float* c5w  = (const float*)d_in[5];
    const float* c5b  = (const float*)d_in[6];
    const float* ldww = (const float*)d_in[7];
    const float* ldwb = (const float*)d_in[8];
    const float* lpww = (const float*)d_in[9];
    const float* lpwb = (const float*)d_in[10];
    const float* s1dw = (const float*)d_in[11];
    const float* s1db = (const float*)d_in[12];
    const float* s1pw = (const float*)d_in[13];
    const float* s1pb = (const float*)d_in[14];
    const float* s2dw = (const float*)d_in[15];
    const float* s2db = (const float*)d_in[16];
    const float* s2pw = (const float*)d_in[17];
    const float* s2pb = (const float*)d_in[18];
    const float* s3dw = (const float*)d_in[19];
    const float* s3db = (const float*)d_in[20];
    const float* s3pw = (const float*)d_in[21];
    const float* s3pb = (const float*)d_in[22];
    const float* s4dw = (const float*)d_in[23];
    const float* s4db = (const float*)d_in[24];
    const float* s4pw = (const float*)d_in[25];
    const float* s4pb = (const float*)d_in[26];

    // workspace layout: y (bf16 NHWC) | z (bf16 NHWC) | st2 (float2) | dwT
    const size_t yBytes  = (size_t)8 * Cch * HWsz * sizeof(unsigned short); // 102,760,448
    const size_t zBytes  = yBytes;                                          // 102,760,448
    const size_t stBytes = (size_t)8 * HWsz * sizeof(float2);               //   3,211,264
    unsigned int*   y_u32 = (unsigned int*)d_ws;
    unsigned short* y_u16 = (unsigned short*)d_ws;
    unsigned int*   z_u32 = (unsigned int*)((char*)d_ws + yBytes);
    unsigned short* z_u16 = (unsigned short*)((char*)d_ws + yBytes);
    float2* st2 = (float2*)((char*)d_ws + yBytes + zBytes);
    float*  dwT = (float*)((char*)d_ws + yBytes + zBytes + stBytes);

    prep<<<dim3(5), 256, 0, stream>>>(ldww, dwT);
    lnT<<<dim3(HWsz / TPX, 8), 256, 0, stream>>>(x, n1w, n1b, y_u32);

    kernelA<<<dim3(W_ / TAW, H_ / TAH, 8), 256, 0, stream>>>(
        y_u16, c5w, c5b,
        s1dw, s1db, s1pw, s1pb,
        s2dw, s2db, s2pw, s2pb,
        s3dw, s3db, s3pw, s3pb,
        s4dw, s4db, s4pw, s4pb, z_u32, st2);

    kernelB<<<dim3(W_ / PBW, H_ / PBH, 8), 256, 0, stream>>>(
        z_u16, st2, n2w, n2b, dwT, ldwb, lpww, lpwb, (float*)d_out);
}

// Round 18
// 445.474 us; speedup vs baseline: 1.5675x; 1.1083x over previous
//
#include <hip/hip_runtime.h>
#include <hip/hip_bf16.h>
#include <math.h>

#define H_   224
#define W_   224
#define HWsz 50176      // 224*224
#define Cch  128

// Kernel A: out tile 8x8, halo 2 -> 12x12
#define TAH 8
#define TAW 8
#define HAH 12
#define HAW 12
#define NHALO_A (HAH*HAW)   // 144  (row 144 = dedicated zero pixel)

// Kernel B: patch 8 rows x 16 cols, halo 1 -> 10x18
#define PBH 8
#define PBW 16
#define HBH 10
#define HBW 18
#define NHALO_B (HBH*HBW)   // 180
#define GPITCH 136          // g_s row pitch in bf16 units (272 B)

// lnT: pixels per block
#define TPX 64

typedef __bf16 bf16x8 __attribute__((ext_vector_type(8)));
typedef float  f32x4  __attribute__((ext_vector_type(4)));

__device__ __forceinline__ float bf2f(__hip_bfloat16 v) { return __bfloat162float(v); }
__device__ __forceinline__ __hip_bfloat16 f2bf(float v) { return __float2bfloat16(v); }
__device__ __forceinline__ float ubf2f(unsigned short u) {
    unsigned x = ((unsigned)u) << 16; return __int_as_float((int)x);
}
__device__ __forceinline__ unsigned short f2ubf(float f) {
    __hip_bfloat16 h = __float2bfloat16(f);
    return *reinterpret_cast<unsigned short*>(&h);
}
// exact GELU (erf) — the fast tanh variant failed post-timing revalidation
// in rounds 14/15; keep the proven-deterministic path.
__device__ __forceinline__ float gelu_exact(float x) {
    return 0.5f * x * (1.0f + erff(x * 0.70710678118654752440f));
}
// readfirstlane a wave-uniform pointer into SGPRs so weight reads become s_loads
__device__ __forceinline__ const float* rflp(const float* p) {
    unsigned long long v = (unsigned long long)p;
    unsigned lo = __builtin_amdgcn_readfirstlane((unsigned)v);
    unsigned hi = __builtin_amdgcn_readfirstlane((unsigned)(v >> 32));
    return (const float*)(((unsigned long long)hi << 32) | lo);
}
__device__ __forceinline__ void unpack8(float* F, uint4 v) {
    F[0] = ubf2f((unsigned short)(v.x & 0xffffu)); F[1] = ubf2f((unsigned short)(v.x >> 16));
    F[2] = ubf2f((unsigned short)(v.y & 0xffffu)); F[3] = ubf2f((unsigned short)(v.y >> 16));
    F[4] = ubf2f((unsigned short)(v.z & 0xffffu)); F[5] = ubf2f((unsigned short)(v.z >> 16));
    F[6] = ubf2f((unsigned short)(v.w & 0xffffu)); F[7] = ubf2f((unsigned short)(v.w >> 16));
}

// =====================================================================
// prep: transpose ldw depthwise weights to dwT[tap][c]
// =====================================================================
__global__ __launch_bounds__(256)
void prep(const float* __restrict__ ldww, float* __restrict__ dwT)
{
    const int i = blockIdx.x * 256 + threadIdx.x;
    if (i < 9 * Cch) {
        const int t = i >> 7, c = i & 127;
        dwT[i] = ldww[c * 9 + t];
    }
}

// =====================================================================
// lnT: LN1 (stats + normalize) + NCHW->NHWC transpose, bf16 out
// =====================================================================
__global__ __launch_bounds__(256, 4)
void lnT(const float* __restrict__ x,
         const float* __restrict__ n1w, const float* __restrict__ n1b,
         unsigned int* __restrict__ y)
{
    __shared__ float xs[TPX][Cch + 1];      // 33,024 B
    __shared__ float rs_[4][TPX], rss_[4][TPX];
    __shared__ float2 st_s[TPX];

    const int t   = threadIdx.x;
    const int b   = blockIdx.y;
    const int sp0 = blockIdx.x * TPX;

    // phase a: coalesced load, transpose into LDS
    {
        const int lane = t & 63, wv = t >> 6;
        const float* xb = x + (size_t)b * Cch * HWsz + sp0 + lane;
        #pragma unroll 8
        for (int k = 0; k < 32; ++k) {
            const int c = wv * 32 + k;
            xs[lane][c] = xb[(size_t)c * HWsz];
        }
    }
    __syncthreads();

    // phase b: per-pixel stats (4 threads per pixel)
    {
        const int p = t & 63, q = t >> 6;
        float s = 0.f, ss = 0.f;
        #pragma unroll
        for (int k = 0; k < 32; ++k) {
            const float v = xs[p][q * 32 + k];
            s += v; ss += v * v;
        }
        rs_[q][p] = s; rss_[q][p] = ss;
    }
    __syncthreads();
    if (t < TPX) {
        const float S  = rs_[0][t] + rs_[1][t] + rs_[2][t] + rs_[3][t];
        const float SS = rss_[0][t] + rss_[1][t] + rss_[2][t] + rss_[3][t];
        const float mu  = S * (1.0f / 128.0f);
        const float var = SS * (1.0f / 128.0f) - mu * mu;
        st_s[t] = make_float2(mu, rsqrtf(var + 1e-6f));
    }
    __syncthreads();

    // phase c: normalize + pack bf16 + coalesced NHWC store
    {
        const int ch = t & 15;          // 16B chunk (8 channels)
        const int pb = t >> 4;          // 0..15
        float w8[8], b8[8];
        #pragma unroll
        for (int j = 0; j < 8; ++j) {
            w8[j] = n1w[ch * 8 + j];
            b8[j] = n1b[ch * 8 + j];
        }
        #pragma unroll
        for (int it = 0; it < 4; ++it) {
            const int p = it * 16 + pb;
            const float2 st = st_s[p];
            unsigned int pk[4];
            #pragma unroll
            for (int u = 0; u < 4; ++u) {
                const int c0 = ch * 8 + u * 2;
                const float v0 = (xs[p][c0]     - st.x) * st.y * w8[u*2]   + b8[u*2];
                const float v1 = (xs[p][c0 + 1] - st.x) * st.y * w8[u*2+1] + b8[u*2+1];
                pk[u] = (unsigned int)f2ubf(v0) | ((unsigned int)f2ubf(v1) << 16);
            }
            *reinterpret_cast<uint4*>(y + ((size_t)b * HWsz + sp0 + p) * 64 + ch * 4) =
                make_uint4(pk[0], pk[1], pk[2], pk[3]);
        }
    }
}

// =====================================================================
// conv_taps: accumulate 9 taps x 32 channels from swizzled NHWC LDS.
// w9 MUST be an SGPR (readfirstlane'd) pointer -> weights are s_loads.
// mask handled by redirecting the tap address to the zero row (144)
// =====================================================================
__device__ __forceinline__ void conv_taps(
    float* __restrict__ G, const uint4* __restrict__ ys4,
    const float* __restrict__ w9,
    int rb, int cb, int chunkBase,
    const bool* rowOK, const bool* colOK, bool useMask)
{
    #pragma unroll
    for (int t3 = 0; t3 < 3; ++t3)
        #pragma unroll
        for (int t4 = 0; t4 < 3; ++t4) {
            const int tap = t3 * 3 + t4;
            int q = (rb + t3) * HAW + (cb + t4);
            if (useMask && !(rowOK[t3] && colOK[t4])) q = NHALO_A;  // zero row
            const char* base = reinterpret_cast<const char*>(ys4) + q * 256;
            const int sw = q & 15;
            #pragma unroll
            for (int u = 0; u < 4; ++u) {
                const uint4 t = *reinterpret_cast<const uint4*>(
                                    base + (((chunkBase + u) ^ sw) << 4));
                const int i0 = u * 8;
                G[i0+0] = fmaf(w9[(i0+0)*9+tap], ubf2f((unsigned short)(t.x & 0xffffu)), G[i0+0]);
                G[i0+1] = fmaf(w9[(i0+1)*9+tap], ubf2f((unsigned short)(t.x >> 16)),     G[i0+1]);
                G[i0+2] = fmaf(w9[(i0+2)*9+tap], ubf2f((unsigned short)(t.y & 0xffffu)), G[i0+2]);
                G[i0+3] = fmaf(w9[(i0+3)*9+tap], ubf2f((unsigned short)(t.y >> 16)),     G[i0+3]);
                G[i0+4] = fmaf(w9[(i0+4)*9+tap], ubf2f((unsigned short)(t.z & 0xffffu)), G[i0+4]);
                G[i0+5] = fmaf(w9[(i0+5)*9+tap], ubf2f((unsigned short)(t.z >> 16)),     G[i0+5]);
                G[i0+6] = fmaf(w9[(i0+6)*9+tap], ubf2f((unsigned short)(t.w & 0xffffu)), G[i0+6]);
                G[i0+7] = fmaf(w9[(i0+7)*9+tap], ubf2f((unsigned short)(t.w >> 16)),     G[i0+7]);
            }
        }
}

// conv16: same, but 16 channels (2 chunks), no mask (c5 path)
__device__ __forceinline__ void conv16(
    float* __restrict__ F, const uint4* __restrict__ ys4,
    const float* __restrict__ w9,
    int rb, int cbq, int chunkBase)
{
    #pragma unroll
    for (int t3 = 0; t3 < 3; ++t3)
        #pragma unroll
        for (int t4 = 0; t4 < 3; ++t4) {
            const int tap = t3 * 3 + t4;
            const int q = (rb + t3) * HAW + (cbq + t4);
            const char* base = reinterpret_cast<const char*>(ys4) + q * 256;
            const int sw = q & 15;
            #pragma unroll
            for (int u = 0; u < 2; ++u) {
                const uint4 t = *reinterpret_cast<const uint4*>(
                                    base + (((chunkBase + u) ^ sw) << 4));
                const int i0 = u * 8;
                F[i0+0] = fmaf(w9[(i0+0)*9+tap], ubf2f((unsigned short)(t.x & 0xffffu)), F[i0+0]);
                F[i0+1] = fmaf(w9[(i0+1)*9+tap], ubf2f((unsigned short)(t.x >> 16)),     F[i0+1]);
                F[i0+2] = fmaf(w9[(i0+2)*9+tap], ubf2f((unsigned short)(t.y & 0xffffu)), F[i0+2]);
                F[i0+3] = fmaf(w9[(i0+3)*9+tap], ubf2f((unsigned short)(t.y >> 16)),     F[i0+3]);
                F[i0+4] = fmaf(w9[(i0+4)*9+tap], ubf2f((unsigned short)(t.z & 0xffffu)), F[i0+4]);
                F[i0+5] = fmaf(w9[(i0+5)*9+tap], ubf2f((unsigned short)(t.z >> 16)),     F[i0+5]);
                F[i0+6] = fmaf(w9[(i0+6)*9+tap], ubf2f((unsigned short)(t.w & 0xffffu)), F[i0+6]);
                F[i0+7] = fmaf(w9[(i0+7)*9+tap], ubf2f((unsigned short)(t.w >> 16)),     F[i0+7]);
            }
        }
}

// =====================================================================
// Kernel A (8x8 tile, wave=chunk): y(NHWC bf16) -> 4 shift branches
// (dw3+GELU in VALU, pw32 via MFMA) -> zx exchange -> phase 3: c5 +
// shuffle-pack -> z (bf16 NHWC) + LN2 stats (cross-wave via zx buffer)
// =====================================================================
__global__ __launch_bounds__(256, 3)
void kernelA(const unsigned short* __restrict__ y,
             const float* __restrict__ c5w, const float* __restrict__ c5b,
             const float* __restrict__ s1dw, const float* __restrict__ s1db,
             const float* __restrict__ s1pw, const float* __restrict__ s1pb,
             const float* __restrict__ s2dw, const float* __restrict__ s2db,
             const float* __restrict__ s2pw, const float* __restrict__ s2pb,
             const float* __restrict__ s3dw, const float* __restrict__ s3db,
             const float* __restrict__ s3pw, const float* __restrict__ s3pb,
             const float* __restrict__ s4dw, const float* __restrict__ s4db,
             const float* __restrict__ s4pw, const float* __restrict__ s4pb,
             unsigned int* __restrict__ zout, float2* __restrict__ st2)
{
    __shared__ uint4 y_s4[(NHALO_A + 1) * 16];   // 37,120 B (incl zero row)
    __shared__ uint4 zx4[TAH * TAW * 16];        // 16,384 B: G-LDS -> z-exchange -> stats

    const int tid = threadIdx.x;
    const int b   = blockIdx.z;
    const int h0  = blockIdx.y * TAH;
    const int w0  = blockIdx.x * TAW;

    // ---------- Phase 1: coalesced NHWC load -> swizzled b128 LDS store ----------
    {
        const int ch = tid & 15;          // 16B chunk (8 channels)
        const int pb = tid >> 4;          // 0..15
        #pragma unroll
        for (int it = 0; it < 9; ++it) {
            const int p  = it * 16 + pb;  // halo pixel index 0..143
            const int ph = p / HAW, pw2 = p - ph * HAW;
            const int gy = h0 - 2 + ph, gx = w0 - 2 + pw2;
            uint4 v = make_uint4(0u, 0u, 0u, 0u);
            if ((unsigned)gy < (unsigned)H_ && (unsigned)gx < (unsigned)W_)
                v = *reinterpret_cast<const uint4*>(
                    y + ((size_t)b * HWsz + (size_t)gy * W_ + gx) * Cch + ch * 8);
            y_s4[p * 16 + (ch ^ pb)] = v;
        }
        if (tid < 16) y_s4[NHALO_A * 16 + tid] = make_uint4(0u, 0u, 0u, 0u);
    }
    __syncthreads();

    // ---------- Phase 2: wave k: dw3+GELU (VALU), pw32 (MFMA) ----------
    {
        const int px  = tid & 63;          // pixel in 8x8 tile (= lane)
        const int k   = tid >> 6;          // chunk id, wave-uniform
        const int py  = px >> 3, pxx = px & 7;
        const int gh  = h0 + py, gw = w0 + pxx;

        bool rowOK[3], colOK[3];
        #pragma unroll
        for (int t = 0; t < 3; ++t) {
            rowOK[t] = (gh - 1 + t >= 0) && (gh - 1 + t < H_);
            colOK[t] = (gw - 1 + t >= 0) && (gw - 1 + t < W_);
        }

        // chunk table: k=0:s1 sh(1,1) | k=1:s2 sh(-1,1) | k=2:s3 sh(-1,-1) | k=3:s4 sh(1,-1)
        const float* dwW = rflp(k == 0 ? s1dw : k == 1 ? s2dw : k == 2 ? s3dw : s4dw);
        const float* dwB = rflp(k == 0 ? s1db : k == 1 ? s2db : k == 2 ? s3db : s4db);
        const float* pwW = rflp(k == 0 ? s1pw : k == 1 ? s2pw : k == 2 ? s3pw : s4pw);
        const float* pwB = rflp(k == 0 ? s1pb : k == 1 ? s2pb : k == 2 ? s3pb : s4pb);
        const int shh = (k == 0 || k == 3) ? 1 : -1;
        const int shw = (k <= 1) ? 1 : -1;

        float G[32];
        #pragma unroll
        for (int i = 0; i < 32; ++i) G[i] = dwB[i];
        conv_taps(G, y_s4, dwW, py + 1 - shh, pxx + 1 - shw, k * 4, rowOK, colOK, true);
        #pragma unroll
        for (int i = 0; i < 32; ++i) G[i] = gelu_exact(G[i]);

        // G -> wave-private LDS region (bf16, 16B-chunk swizzled by px&3)
        uint4* Gk = zx4 + k * 256;
        #pragma unroll
        for (int c = 0; c < 4; ++c) {
            uint4 o;
            o.x = (unsigned)f2ubf(G[c*8+0]) | ((unsigned)f2ubf(G[c*8+1]) << 16);
            o.y = (unsigned)f2ubf(G[c*8+2]) | ((unsigned)f2ubf(G[c*8+3]) << 16);
            o.z = (unsigned)f2ubf(G[c*8+4]) | ((unsigned)f2ubf(G[c*8+5]) << 16);
            o.w = (unsigned)f2ubf(G[c*8+6]) | ((unsigned)f2ubf(G[c*8+7]) << 16);
            Gk[px * 4 + (c ^ (px & 3))] = o;
        }
        __builtin_amdgcn_sched_barrier(0);   // keep ds_reads after ds_writes

        // A-fragments (pwW -> bf16) and bias-initialized accumulators.
        // D[out][px]: lane holds col=px=(l&15), row=out=(l>>4)*4+r.
        bf16x8 afr[2];
        f32x4  acc[2][4];
        #pragma unroll
        for (int at = 0; at < 2; ++at) {
            const float* wp = pwW + (at * 16 + (px & 15)) * 32 + (px >> 4) * 8;
            const float4 wa = *reinterpret_cast<const float4*>(wp);
            const float4 wb = *reinterpret_cast<const float4*>(wp + 4);
            bf16x8 v;
            v[0] = (__bf16)wa.x; v[1] = (__bf16)wa.y; v[2] = (__bf16)wa.z; v[3] = (__bf16)wa.w;
            v[4] = (__bf16)wb.x; v[5] = (__bf16)wb.y; v[6] = (__bf16)wb.z; v[7] = (__bf16)wb.w;
            afr[at] = v;
            const float4 bi = *reinterpret_cast<const float4*>(pwB + at * 16 + (px >> 4) * 4);
            #pragma unroll
            for (int bt = 0; bt < 4; ++bt) {
                acc[at][bt][0] = bi.x; acc[at][bt][1] = bi.y;
                acc[at][bt][2] = bi.z; acc[at][bt][3] = bi.w;
            }
        }
        // 8 MFMAs: B = own-wave G (k-slices per lane)
        #pragma unroll
        for (int bt = 0; bt < 4; ++bt) {
            const int p2 = bt * 16 + (px & 15);
            const bf16x8 bfg = *reinterpret_cast<const bf16x8*>(
                &Gk[p2 * 4 + ((px >> 4) ^ (px & 3))]);
            #pragma unroll
            for (int at = 0; at < 2; ++at)
                acc[at][bt] = __builtin_amdgcn_mfma_f32_16x16x32_bf16(
                                  afr[at], bfg, acc[at][bt], 0, 0, 0);
        }
        __syncthreads();   // all waves done reading their G region

        // store pw result to zx exchange: [px][k*32 + j] bf16, chunk-swizzled
        #pragma unroll
        for (int at = 0; at < 2; ++at)
            #pragma unroll
            for (int bt = 0; bt < 4; ++bt) {
                const int p2  = bt * 16 + (px & 15);
                const int jj  = at * 16 + ((px >> 4) << 2);   // local out base (4 ch)
                const int ck  = k * 4 + (jj >> 3);
                const int sub = (jj >> 2) & 1;
                uint2 o;
                o.x = (unsigned)f2ubf(acc[at][bt][0]) | ((unsigned)f2ubf(acc[at][bt][1]) << 16);
                o.y = (unsigned)f2ubf(acc[at][bt][2]) | ((unsigned)f2ubf(acc[at][bt][3]) << 16);
                *reinterpret_cast<uint2*>(
                    reinterpret_cast<char*>(zx4) + p2 * 256 +
                    ((ck ^ (p2 & 15)) << 4) + sub * 8) = o;
            }
    }
    __syncthreads();

    // ---------- Phase 3: wave s = z-segment; lane = pixel.
    // c5 + shuffle-interleave + pack + store + LN2 stats ----------
    {
        const int s   = tid >> 6;          // segment 0..3 (wave-uniform)
        const int p3  = tid & 63;          // pixel
        const int py3 = p3 >> 3, px3 = p3 & 7;
        const int gh3 = h0 + py3, gw3 = w0 + px3;
        const int sw  = p3 & 15;
        const int klo = (s < 2) ? 1 : 3;
        const int khi = (s < 2) ? 0 : 2;
        const int cb  = (s & 1) * 2;

        const uint4 lo0 = zx4[p3 * 16 + ((klo * 4 + cb)     ^ sw)];
        const uint4 lo1 = zx4[p3 * 16 + ((klo * 4 + cb + 1) ^ sw)];
        const uint4 hi0 = zx4[p3 * 16 + ((khi * 4 + cb)     ^ sw)];
        const uint4 hi1 = zx4[p3 * 16 + ((khi * 4 + cb + 1) ^ sw)];
        __syncthreads();   // zx4 pw data consumed block-wide; reusable for stats

        float Flo[16], Fhi[16];
        unpack8(Flo,     lo0); unpack8(Flo + 8, lo1);
        unpack8(Fhi,     hi0); unpack8(Fhi + 8, hi1);

        // pre-shuffle channel bases: ob(k=1)=0, ob(k=3)=32, ob(k=0)=64, ob(k=2)=96
        const int obLo = (s < 2) ? 0  : 32;
        const int obHi = (s < 2) ? 64 : 96;
        const float* c5wL = rflp(c5w + (obLo + cb * 8) * 9);
        const float* c5bL = rflp(c5b +  obLo + cb * 8);
        const float* c5wH = rflp(c5w + (obHi + cb * 8) * 9);
        const float* c5bH = rflp(c5b +  obHi + cb * 8);
        #pragma unroll
        for (int i = 0; i < 16; ++i) { Flo[i] += c5bL[i]; Fhi[i] += c5bH[i]; }
        conv16(Flo, y_s4, c5wL, py3 + 1, px3 + 1, (obLo >> 3) + cb);
        conv16(Fhi, y_s4, c5wH, py3 + 1, px3 + 1, (obHi >> 3) + cb);

        float s1 = 0.f, s2 = 0.f;
        unsigned pk[16];
        #pragma unroll
        for (int i = 0; i < 16; ++i) {
            const unsigned short lo = f2ubf(Flo[i]);
            const unsigned short hi = f2ubf(Fhi[i]);
            const float fl = ubf2f(lo), fh = ubf2f(hi);
            s1 += fl + fh; s2 += fl * fl + fh * fh;
            pk[i] = (unsigned)lo | ((unsigned)hi << 16);
        }
        unsigned int* zp = zout + ((size_t)b * HWsz + (size_t)gh3 * W_ + gw3) * 64 + s * 16;
        *reinterpret_cast<uint4*>(zp + 0)  = make_uint4(pk[0],  pk[1],  pk[2],  pk[3]);
        *reinterpret_cast<uint4*>(zp + 4)  = make_uint4(pk[4],  pk[5],  pk[6],  pk[7]);
        *reinterpret_cast<uint4*>(zp + 8)  = make_uint4(pk[8],  pk[9],  pk[10], pk[11]);
        *reinterpret_cast<uint4*>(zp + 12) = make_uint4(pk[12], pk[13], pk[14], pk[15]);

        // LN2 stats: cross-wave reduce through the now-dead zx4 buffer
        float* red = reinterpret_cast<float*>(zx4);
        red[s * 64 + p3]       = s1;
        red[256 + s * 64 + p3] = s2;
        __syncthreads();
        if (s == 0) {
            const float S  = red[p3] + red[64 + p3] + red[128 + p3] + red[192 + p3];
            const float SS = red[256 + p3] + red[320 + p3] + red[384 + p3] + red[448 + p3];
            const float mu  = S * (1.0f / 128.0f);
            const float var = SS * (1.0f / 128.0f) - mu * mu;
            st2[(size_t)b * HWsz + (size_t)gh3 * W_ + gw3] = make_float2(mu, rsqrtf(var + 1e-6f));
        }
    }
}

// =====================================================================
// Kernel B: stage LN2(z)-halo in LDS (bf16, swizzled NHWC) ->
//           dw3 + GELU from LDS -> g_s -> 128x128 pointwise via MFMA
// =====================================================================
__global__ __launch_bounds__(256, 2)
void kernelB(const unsigned short* __restrict__ z, const float2* __restrict__ st2,
             const float* __restrict__ n2w, const float* __restrict__ n2b,
             const float* __restrict__ dwT, const float* __restrict__ dwB,
             const float* __restrict__ pwW, const float* __restrict__ pwB,
             float* __restrict__ out)
{
    __shared__ uint4 w_s4[NHALO_B * 16];                 // 46,080 B
    __shared__ unsigned short g_s[PBH * PBW * GPITCH];   // 34,816 B

    const int tid  = threadIdx.x;
    const int lane = tid & 63;
    const int wv   = tid >> 6;
    const int b    = blockIdx.z;
    const int h0   = blockIdx.y * PBH;
    const int w0   = blockIdx.x * PBW;

    // ---------------- Phase S: stage LN2-normalized halo into w_s4 ----------------
    {
        const int ch = tid & 15;          // 16B chunk (8 channels)
        const int pb = tid >> 4;          // 0..15
        float nw[8], nb[8];
        #pragma unroll
        for (int j = 0; j < 8; ++j) {
            nw[j] = n2w[ch * 8 + j];
            nb[j] = n2b[ch * 8 + j];
        }
        #pragma unroll
        for (int it = 0; it < 12; ++it) {
            const int p = it * 16 + pb;   // halo pixel 0..179
            if (p < NHALO_B) {
                const int ph = p / HBW, pw2 = p - ph * HBW;
                const int gy = h0 - 1 + ph, gx = w0 - 1 + pw2;
                uint4 o = make_uint4(0u, 0u, 0u, 0u);
                if ((unsigned)gy < (unsigned)H_ && (unsigned)gx < (unsigned)W_) {
                    const size_t pp = (size_t)b * HWsz + (size_t)gy * W_ + gx;
                    const uint4 zv = *reinterpret_cast<const uint4*>(z + pp * Cch + ch * 8);
                    const float2 st = st2[pp];
                    const float f0 = (ubf2f((unsigned short)(zv.x & 0xffffu)) - st.x) * st.y * nw[0] + nb[0];
                    const float f1 = (ubf2f((unsigned short)(zv.x >> 16))     - st.x) * st.y * nw[1] + nb[1];
                    const float f2 = (ubf2f((unsigned short)(zv.y & 0xffffu)) - st.x) * st.y * nw[2] + nb[2];
                    const float f3 = (ubf2f((unsigned short)(zv.y >> 16))     - st.x) * st.y * nw[3] + nb[3];
                    const float f4 = (ubf2f((unsigned short)(zv.z & 0xffffu)) - st.x) * st.y * nw[4] + nb[4];
                    const float f5 = (ubf2f((unsigned short)(zv.z >> 16))     - st.x) * st.y * nw[5] + nb[5];
                    const float f6 = (ubf2f((unsigned short)(zv.w & 0xffffu)) - st.x) * st.y * nw[6] + nb[6];
                    const float f7 = (ubf2f((unsigned short)(zv.w >> 16))     - st.x) * st.y * nw[7] + nb[7];
                    o.x = (unsigned)f2ubf(f0) | ((unsigned)f2ubf(f1) << 16);
                    o.y = (unsigned)f2ubf(f2) | ((unsigned)f2ubf(f3) << 16);
                    o.z = (unsigned)f2ubf(f4) | ((unsigned)f2ubf(f5) << 16);
                    o.w = (unsigned)f2ubf(f6) | ((unsigned)f2ubf(f7) << 16);
                }
                w_s4[p * 16 + (ch ^ (p & 15))] = o;
            }
        }
    }
    __syncthreads();

    // ---------------- Phase L: dw3 + GELU from LDS -> g_s (bf16) ----------------
    {
        const int cc = lane & 15;          // channel chunk (8 ch)
        const int sl = lane >> 4;          // 0..3
        const int s  = wv * 4 + sl;        // col in patch 0..15
        const int cbase = cc * 8;

        float db[8];
        float wt[9][8];
        #pragma unroll
        for (int j = 0; j < 8; ++j) db[j] = dwB[cbase + j];
        #pragma unroll
        for (int t = 0; t < 9; ++t)
            #pragma unroll
            for (int j = 0; j < 8; ++j)
                wt[t][j] = dwT[t * Cch + cbase + j];

        for (int r = 0; r < PBH; ++r) {
            float a[8];
            #pragma unroll
            for (int j = 0; j < 8; ++j) a[j] = db[j];

            #pragma unroll
            for (int dy = 0; dy < 3; ++dy)
                #pragma unroll
                for (int dx = 0; dx < 3; ++dx) {
                    const int tap = dy * 3 + dx;
                    const int q = (r + dy) * HBW + (s + dx);
                    const uint4 t4 = w_s4[q * 16 + (cc ^ (q & 15))];
                    a[0] = fmaf(wt[tap][0], ubf2f((unsigned short)(t4.x & 0xffffu)), a[0]);
                    a[1] = fmaf(wt[tap][1], ubf2f((unsigned short)(t4.x >> 16)),     a[1]);
                    a[2] = fmaf(wt[tap][2], ubf2f((unsigned short)(t4.y & 0xffffu)), a[2]);
                    a[3] = fmaf(wt[tap][3], ubf2f((unsigned short)(t4.y >> 16)),     a[3]);
                    a[4] = fmaf(wt[tap][4], ubf2f((unsigned short)(t4.z & 0xffffu)), a[4]);
                    a[5] = fmaf(wt[tap][5], ubf2f((unsigned short)(t4.z >> 16)),     a[5]);
                    a[6] = fmaf(wt[tap][6], ubf2f((unsigned short)(t4.w & 0xffffu)), a[6]);
                    a[7] = fmaf(wt[tap][7], ubf2f((unsigned short)(t4.w >> 16)),     a[7]);
                }

            unsigned int pk[4];
            #pragma unroll
            for (int q = 0; q < 4; ++q) {
                const unsigned short lo = f2ubf(gelu_exact(a[2*q]));
                const unsigned short hi = f2ubf(gelu_exact(a[2*q+1]));
                pk[q] = (unsigned int)lo | ((unsigned int)hi << 16);
            }
            const int row = r * PBW + s;
            const int boff = row * (GPITCH * 2) + ((cbase * 2) ^ ((row & 3) << 4));
            *reinterpret_cast<uint4*>(reinterpret_cast<char*>(g_s) + boff) =
                make_uint4(pk[0], pk[1], pk[2], pk[3]);
        }
    }
    __syncthreads();

    // ---------------- Phase P: 128x128 pointwise via MFMA ----------------
    {
        const int ll = lane & 15;
        const int lh = lane >> 4;

        bf16x8 bfr[2][4];
        float  pb[2];
        #pragma unroll
        for (int t2 = 0; t2 < 2; ++t2) {
            const int o = (wv * 2 + t2) * 16 + ll;
            pb[t2] = pwB[o];
            #pragma unroll
            for (int kt = 0; kt < 4; ++kt) {
                const float* wp = pwW + (size_t)o * Cch + kt * 32 + lh * 8;
                bf16x8 vv;
                #pragma unroll
                for (int j = 0; j < 8; ++j) vv[j] = (__bf16)wp[j];
                bfr[t2][kt] = vv;
            }
        }

        #pragma unroll
        for (int r = 0; r < PBH; ++r) {
            const int row = r * PBW + ll;
            bf16x8 af[4];
            #pragma unroll
            for (int kt = 0; kt < 4; ++kt) {
                const int boff = row * (GPITCH * 2) + ((kt * 64 + lh * 16) ^ ((row & 3) << 4));
                af[kt] = *reinterpret_cast<const bf16x8*>(
                            reinterpret_cast<const char*>(g_s) + boff);
            }
            #pragma unroll
            for (int t2 = 0; t2 < 2; ++t2) {
                f32x4 acc = {0.f, 0.f, 0.f, 0.f};
                #pragma unroll
                for (int kt = 0; kt < 4; ++kt)
                    acc = __builtin_amdgcn_mfma_f32_16x16x32_bf16(af[kt], bfr[t2][kt], acc, 0, 0, 0);
                const int o = (wv * 2 + t2) * 16 + ll;
                float4 res = make_float4(acc[0] + pb[t2], acc[1] + pb[t2],
                                         acc[2] + pb[t2], acc[3] + pb[t2]);
                *reinterpret_cast<float4*>(
                    out + ((size_t)b * Cch + o) * HWsz + (size_t)(h0 + r) * W_ + w0 + lh * 4) = res;
            }
        }
    }
}

// =====================================================================
extern "C" void kernel_launch(void* const* d_in, const int* in_sizes, int n_in,
                              void* d_out, int out_size, void* d_ws, size_t ws_size,
                              hipStream_t stream)
{
    const float* x    = (const float*)d_in[0];
    const float* n1w  = (const float*)d_in[1];
    const float* n1b  = (const float*)d_in[2];
    const float* n2w  = (const float*)d_in[3];
    const float* n2b  = (const float*)d_in[4];
    const float* c5w  = (const float*)d_in[5];
    const float* c5b  = (const float*)d_in[6];
    const float* ldww = (const float*)d_in[7];
    const float* ldwb = (const float*)d_in[8];
    const float* lpww = (const float*)d_in[9];
    const float* lpwb = (const float*)d_in[10];
    const float* s1dw = (const float*)d_in[11];
    const float* s1db = (const float*)d_in[12];
    const float* s1pw = (const float*)d_in[13];
    const float* s1pb = (const float*)d_in[14];
    const float* s2dw = (const float*)d_in[15];
    const float* s2db = (const float*)d_in[16];
    const float* s2pw = (const float*)d_in[17];
    const float* s2pb = (const float*)d_in[18];
    const float* s3dw = (const float*)d_in[19];
    const float* s3db = (const float*)d_in[20];
    const float* s3pw = (const float*)d_in[21];
    const float* s3pb = (const float*)d_in[22];
    const float* s4dw = (const float*)d_in[23];
    const float* s4db = (const float*)d_in[24];
    const float* s4pw = (const float*)d_in[25];
    const float* s4pb = (const float*)d_in[26];

    // workspace layout: y (bf16 NHWC) | z (bf16 NHWC) | st2 (float2) | dwT
    const size_t yBytes  = (size_t)8 * Cch * HWsz * sizeof(unsigned short); // 102,760,448
    const size_t zBytes  = yBytes;                                          // 102,760,448
    const size_t stBytes = (size_t)8 * HWsz * sizeof(float2);               //   3,211,264
    unsigned int*   y_u32 = (unsigned int*)d_ws;
    unsigned short* y_u16 = (unsigned short*)d_ws;
    unsigned int*   z_u32 = (unsigned int*)((char*)d_ws + yBytes);
    unsigned short* z_u16 = (unsigned short*)((char*)d_ws + yBytes);
    float2* st2 = (float2*)((char*)d_ws + yBytes + zBytes);
    float*  dwT = (float*)((char*)d_ws + yBytes + zBytes + stBytes);

    prep<<<dim3(5), 256, 0, stream>>>(ldww, dwT);
    lnT<<<dim3(HWsz / TPX, 8), 256, 0, stream>>>(x, n1w, n1b, y_u32);

    kernelA<<<dim3(W_ / TAW, H_ / TAH, 8), 256, 0, stream>>>(
        y_u16, c5w, c5b,
        s1dw, s1db, s1pw, s1pb,
        s2dw, s2db, s2pw, s2pb,
        s3dw, s3db, s3pw, s3pb,
        s4dw, s4db, s4pw, s4pb, z_u32, st2);

    kernelB<<<dim3(W_ / PBW, H_ / PBH, 8), 256, 0, stream>>>(
        z_u16, st2, n2w, n2b, dwT, ldwb, lpww, lpwb, (float*)d_out);
}

// Round 19
// 433.936 us; speedup vs baseline: 1.6092x; 1.0266x over previous
//
#include <hip/hip_runtime.h>
#include <hip/hip_bf16.h>
#include <math.h>

#define H_   224
#define W_   224
#define HWsz 50176      // 224*224
#define Cch  128

// Kernel A: out tile 8x8, halo 2 -> 12x12
#define TAH 8
#define TAW 8
#define HAH 12
#define HAW 12
#define NHALO_A (HAH*HAW)   // 144  (row 144 = dedicated zero pixel)

// Kernel B: patch 8 rows x 16 cols, halo 1 -> 10x18
#define PBH 8
#define PBW 16
#define HBH 10
#define HBW 18
#define NHALO_B (HBH*HBW)   // 180
#define GPITCH 136          // g_s row pitch in bf16 units (272 B)

// lnT: pixels per block
#define TPX 64

typedef __bf16 bf16x8 __attribute__((ext_vector_type(8)));
typedef float  f32x4  __attribute__((ext_vector_type(4)));

__device__ __forceinline__ float bf2f(__hip_bfloat16 v) { return __bfloat162float(v); }
__device__ __forceinline__ __hip_bfloat16 f2bf(float v) { return __float2bfloat16(v); }
__device__ __forceinline__ float ubf2f(unsigned short u) {
    unsigned x = ((unsigned)u) << 16; return __int_as_float((int)x);
}
__device__ __forceinline__ unsigned short f2ubf(float f) {
    __hip_bfloat16 h = __float2bfloat16(f);
    return *reinterpret_cast<unsigned short*>(&h);
}
// exact GELU (erf) — the fast tanh variant failed post-timing revalidation
// in rounds 14/15; keep the proven-deterministic path.
__device__ __forceinline__ float gelu_exact(float x) {
    return 0.5f * x * (1.0f + erff(x * 0.70710678118654752440f));
}
// readfirstlane a wave-uniform pointer into SGPRs so weight reads become s_loads
__device__ __forceinline__ const float* rflp(const float* p) {
    unsigned long long v = (unsigned long long)p;
    unsigned lo = __builtin_amdgcn_readfirstlane((unsigned)v);
    unsigned hi = __builtin_amdgcn_readfirstlane((unsigned)(v >> 32));
    return (const float*)(((unsigned long long)hi << 32) | lo);
}
__device__ __forceinline__ void unpack8(float* F, uint4 v) {
    F[0] = ubf2f((unsigned short)(v.x & 0xffffu)); F[1] = ubf2f((unsigned short)(v.x >> 16));
    F[2] = ubf2f((unsigned short)(v.y & 0xffffu)); F[3] = ubf2f((unsigned short)(v.y >> 16));
    F[4] = ubf2f((unsigned short)(v.z & 0xffffu)); F[5] = ubf2f((unsigned short)(v.z >> 16));
    F[6] = ubf2f((unsigned short)(v.w & 0xffffu)); F[7] = ubf2f((unsigned short)(v.w >> 16));
}

// =====================================================================
// prep: transpose ldw depthwise weights to dwT[tap][c]
// =====================================================================
__global__ __launch_bounds__(256)
void prep(const float* __restrict__ ldww, float* __restrict__ dwT)
{
    const int i = blockIdx.x * 256 + threadIdx.x;
    if (i < 9 * Cch) {
        const int t = i >> 7, c = i & 127;
        dwT[i] = ldww[c * 9 + t];
    }
}

// =====================================================================
// lnT: LN1 (stats + normalize) + NCHW->NHWC transpose, bf16 out
// =====================================================================
__global__ __launch_bounds__(256, 4)
void lnT(const float* __restrict__ x,
         const float* __restrict__ n1w, const float* __restrict__ n1b,
         unsigned int* __restrict__ y)
{
    __shared__ float xs[TPX][Cch + 1];      // 33,024 B
    __shared__ float rs_[4][TPX], rss_[4][TPX];
    __shared__ float2 st_s[TPX];

    const int t   = threadIdx.x;
    const int b   = blockIdx.y;
    const int sp0 = blockIdx.x * TPX;

    // phase a: coalesced load, transpose into LDS
    {
        const int lane = t & 63, wv = t >> 6;
        const float* xb = x + (size_t)b * Cch * HWsz + sp0 + lane;
        #pragma unroll 8
        for (int k = 0; k < 32; ++k) {
            const int c = wv * 32 + k;
            xs[lane][c] = xb[(size_t)c * HWsz];
        }
    }
    __syncthreads();

    // phase b: per-pixel stats (4 threads per pixel)
    {
        const int p = t & 63, q = t >> 6;
        float s = 0.f, ss = 0.f;
        #pragma unroll
        for (int k = 0; k < 32; ++k) {
            const float v = xs[p][q * 32 + k];
            s += v; ss += v * v;
        }
        rs_[q][p] = s; rss_[q][p] = ss;
    }
    __syncthreads();
    if (t < TPX) {
        const float S  = rs_[0][t] + rs_[1][t] + rs_[2][t] + rs_[3][t];
        const float SS = rss_[0][t] + rss_[1][t] + rss_[2][t] + rss_[3][t];
        const float mu  = S * (1.0f / 128.0f);
        const float var = SS * (1.0f / 128.0f) - mu * mu;
        st_s[t] = make_float2(mu, rsqrtf(var + 1e-6f));
    }
    __syncthreads();

    // phase c: normalize + pack bf16 + coalesced NHWC store
    {
        const int ch = t & 15;          // 16B chunk (8 channels)
        const int pb = t >> 4;          // 0..15
        float w8[8], b8[8];
        #pragma unroll
        for (int j = 0; j < 8; ++j) {
            w8[j] = n1w[ch * 8 + j];
            b8[j] = n1b[ch * 8 + j];
        }
        #pragma unroll
        for (int it = 0; it < 4; ++it) {
            const int p = it * 16 + pb;
            const float2 st = st_s[p];
            unsigned int pk[4];
            #pragma unroll
            for (int u = 0; u < 4; ++u) {
                const int c0 = ch * 8 + u * 2;
                const float v0 = (xs[p][c0]     - st.x) * st.y * w8[u*2]   + b8[u*2];
                const float v1 = (xs[p][c0 + 1] - st.x) * st.y * w8[u*2+1] + b8[u*2+1];
                pk[u] = (unsigned int)f2ubf(v0) | ((unsigned int)f2ubf(v1) << 16);
            }
            *reinterpret_cast<uint4*>(y + ((size_t)b * HWsz + sp0 + p) * 64 + ch * 4) =
                make_uint4(pk[0], pk[1], pk[2], pk[3]);
        }
    }
}

// =====================================================================
// conv_taps: accumulate 9 taps x 32 channels from swizzled NHWC LDS.
// w9 MUST be an SGPR (readfirstlane'd) pointer -> weights are s_loads.
// mask handled by redirecting the tap address to the zero row (144)
// =====================================================================
__device__ __forceinline__ void conv_taps(
    float* __restrict__ G, const uint4* __restrict__ ys4,
    const float* __restrict__ w9,
    int rb, int cb, int chunkBase,
    const bool* rowOK, const bool* colOK, bool useMask)
{
    #pragma unroll
    for (int t3 = 0; t3 < 3; ++t3)
        #pragma unroll
        for (int t4 = 0; t4 < 3; ++t4) {
            const int tap = t3 * 3 + t4;
            int q = (rb + t3) * HAW + (cb + t4);
            if (useMask && !(rowOK[t3] && colOK[t4])) q = NHALO_A;  // zero row
            const char* base = reinterpret_cast<const char*>(ys4) + q * 256;
            const int sw = q & 15;
            #pragma unroll
            for (int u = 0; u < 4; ++u) {
                const uint4 t = *reinterpret_cast<const uint4*>(
                                    base + (((chunkBase + u) ^ sw) << 4));
                const int i0 = u * 8;
                G[i0+0] = fmaf(w9[(i0+0)*9+tap], ubf2f((unsigned short)(t.x & 0xffffu)), G[i0+0]);
                G[i0+1] = fmaf(w9[(i0+1)*9+tap], ubf2f((unsigned short)(t.x >> 16)),     G[i0+1]);
                G[i0+2] = fmaf(w9[(i0+2)*9+tap], ubf2f((unsigned short)(t.y & 0xffffu)), G[i0+2]);
                G[i0+3] = fmaf(w9[(i0+3)*9+tap], ubf2f((unsigned short)(t.y >> 16)),     G[i0+3]);
                G[i0+4] = fmaf(w9[(i0+4)*9+tap], ubf2f((unsigned short)(t.z & 0xffffu)), G[i0+4]);
                G[i0+5] = fmaf(w9[(i0+5)*9+tap], ubf2f((unsigned short)(t.z >> 16)),     G[i0+5]);
                G[i0+6] = fmaf(w9[(i0+6)*9+tap], ubf2f((unsigned short)(t.w & 0xffffu)), G[i0+6]);
                G[i0+7] = fmaf(w9[(i0+7)*9+tap], ubf2f((unsigned short)(t.w >> 16)),     G[i0+7]);
            }
        }
}

// conv16: same, but 16 channels (2 chunks), no mask (c5 path)
__device__ __forceinline__ void conv16(
    float* __restrict__ F, const uint4* __restrict__ ys4,
    const float* __restrict__ w9,
    int rb, int cbq, int chunkBase)
{
    #pragma unroll
    for (int t3 = 0; t3 < 3; ++t3)
        #pragma unroll
        for (int t4 = 0; t4 < 3; ++t4) {
            const int tap = t3 * 3 + t4;
            const int q = (rb + t3) * HAW + (cbq + t4);
            const char* base = reinterpret_cast<const char*>(ys4) + q * 256;
            const int sw = q & 15;
            #pragma unroll
            for (int u = 0; u < 2; ++u) {
                const uint4 t = *reinterpret_cast<const uint4*>(
                                    base + (((chunkBase + u) ^ sw) << 4));
                const int i0 = u * 8;
                F[i0+0] = fmaf(w9[(i0+0)*9+tap], ubf2f((unsigned short)(t.x & 0xffffu)), F[i0+0]);
                F[i0+1] = fmaf(w9[(i0+1)*9+tap], ubf2f((unsigned short)(t.x >> 16)),     F[i0+1]);
                F[i0+2] = fmaf(w9[(i0+2)*9+tap], ubf2f((unsigned short)(t.y & 0xffffu)), F[i0+2]);
                F[i0+3] = fmaf(w9[(i0+3)*9+tap], ubf2f((unsigned short)(t.y >> 16)),     F[i0+3]);
                F[i0+4] = fmaf(w9[(i0+4)*9+tap], ubf2f((unsigned short)(t.z & 0xffffu)), F[i0+4]);
                F[i0+5] = fmaf(w9[(i0+5)*9+tap], ubf2f((unsigned short)(t.z >> 16)),     F[i0+5]);
                F[i0+6] = fmaf(w9[(i0+6)*9+tap], ubf2f((unsigned short)(t.w & 0xffffu)), F[i0+6]);
                F[i0+7] = fmaf(w9[(i0+7)*9+tap], ubf2f((unsigned short)(t.w >> 16)),     F[i0+7]);
            }
        }
}

// =====================================================================
// Kernel A (8x8 tile, wave=chunk): y(NHWC bf16) -> 4 shift branches
// (dw3+GELU in VALU, pw32 via MFMA) -> zx exchange -> phase 3a: c5 +
// interleave back to zx -> phase 3b: coalesced z store + LN2 stats
// =====================================================================
__global__ __launch_bounds__(256, 3)
void kernelA(const unsigned short* __restrict__ y,
             const float* __restrict__ c5w, const float* __restrict__ c5b,
             const float* __restrict__ s1dw, const float* __restrict__ s1db,
             const float* __restrict__ s1pw, const float* __restrict__ s1pb,
             const float* __restrict__ s2dw, const float* __restrict__ s2db,
             const float* __restrict__ s2pw, const float* __restrict__ s2pb,
             const float* __restrict__ s3dw, const float* __restrict__ s3db,
             const float* __restrict__ s3pw, const float* __restrict__ s3pb,
             const float* __restrict__ s4dw, const float* __restrict__ s4db,
             const float* __restrict__ s4pw, const float* __restrict__ s4pb,
             unsigned int* __restrict__ zout, float2* __restrict__ st2)
{
    __shared__ uint4 y_s4[(NHALO_A + 1) * 16];   // 37,120 B (incl zero row)
    __shared__ uint4 zx4[TAH * TAW * 16];        // 16,384 B: G-LDS -> pw-exch -> z-exch

    const int tid = threadIdx.x;
    const int b   = blockIdx.z;
    const int h0  = blockIdx.y * TAH;
    const int w0  = blockIdx.x * TAW;

    // ---------- Phase 1: coalesced NHWC load -> swizzled b128 LDS store ----------
    {
        const int ch = tid & 15;          // 16B chunk (8 channels)
        const int pb = tid >> 4;          // 0..15
        #pragma unroll
        for (int it = 0; it < 9; ++it) {
            const int p  = it * 16 + pb;  // halo pixel index 0..143
            const int ph = p / HAW, pw2 = p - ph * HAW;
            const int gy = h0 - 2 + ph, gx = w0 - 2 + pw2;
            uint4 v = make_uint4(0u, 0u, 0u, 0u);
            if ((unsigned)gy < (unsigned)H_ && (unsigned)gx < (unsigned)W_)
                v = *reinterpret_cast<const uint4*>(
                    y + ((size_t)b * HWsz + (size_t)gy * W_ + gx) * Cch + ch * 8);
            y_s4[p * 16 + (ch ^ pb)] = v;
        }
        if (tid < 16) y_s4[NHALO_A * 16 + tid] = make_uint4(0u, 0u, 0u, 0u);
    }
    __syncthreads();

    // ---------- Phase 2: wave k: dw3+GELU (VALU), pw32 (MFMA) ----------
    {
        const int px  = tid & 63;          // pixel in 8x8 tile (= lane)
        const int k   = tid >> 6;          // chunk id, wave-uniform
        const int py  = px >> 3, pxx = px & 7;
        const int gh  = h0 + py, gw = w0 + pxx;

        bool rowOK[3], colOK[3];
        #pragma unroll
        for (int t = 0; t < 3; ++t) {
            rowOK[t] = (gh - 1 + t >= 0) && (gh - 1 + t < H_);
            colOK[t] = (gw - 1 + t >= 0) && (gw - 1 + t < W_);
        }

        // chunk table: k=0:s1 sh(1,1) | k=1:s2 sh(-1,1) | k=2:s3 sh(-1,-1) | k=3:s4 sh(1,-1)
        const float* dwW = rflp(k == 0 ? s1dw : k == 1 ? s2dw : k == 2 ? s3dw : s4dw);
        const float* dwB = rflp(k == 0 ? s1db : k == 1 ? s2db : k == 2 ? s3db : s4db);
        const float* pwW = rflp(k == 0 ? s1pw : k == 1 ? s2pw : k == 2 ? s3pw : s4pw);
        const float* pwB = rflp(k == 0 ? s1pb : k == 1 ? s2pb : k == 2 ? s3pb : s4pb);
        const int shh = (k == 0 || k == 3) ? 1 : -1;
        const int shw = (k <= 1) ? 1 : -1;

        float G[32];
        #pragma unroll
        for (int i = 0; i < 32; ++i) G[i] = dwB[i];
        conv_taps(G, y_s4, dwW, py + 1 - shh, pxx + 1 - shw, k * 4, rowOK, colOK, true);
        #pragma unroll
        for (int i = 0; i < 32; ++i) G[i] = gelu_exact(G[i]);

        // G -> wave-private LDS region (bf16, 16B-chunk swizzled by px&3)
        uint4* Gk = zx4 + k * 256;
        #pragma unroll
        for (int c = 0; c < 4; ++c) {
            uint4 o;
            o.x = (unsigned)f2ubf(G[c*8+0]) | ((unsigned)f2ubf(G[c*8+1]) << 16);
            o.y = (unsigned)f2ubf(G[c*8+2]) | ((unsigned)f2ubf(G[c*8+3]) << 16);
            o.z = (unsigned)f2ubf(G[c*8+4]) | ((unsigned)f2ubf(G[c*8+5]) << 16);
            o.w = (unsigned)f2ubf(G[c*8+6]) | ((unsigned)f2ubf(G[c*8+7]) << 16);
            Gk[px * 4 + (c ^ (px & 3))] = o;
        }
        __builtin_amdgcn_sched_barrier(0);   // keep ds_reads after ds_writes

        // A-fragments (pwW -> bf16) and bias-initialized accumulators.
        // D[out][px]: lane holds col=px=(l&15), row=out=(l>>4)*4+r.
        bf16x8 afr[2];
        f32x4  acc[2][4];
        #pragma unroll
        for (int at = 0; at < 2; ++at) {
            const float* wp = pwW + (at * 16 + (px & 15)) * 32 + (px >> 4) * 8;
            const float4 wa = *reinterpret_cast<const float4*>(wp);
            const float4 wb = *reinterpret_cast<const float4*>(wp + 4);
            bf16x8 v;
            v[0] = (__bf16)wa.x; v[1] = (__bf16)wa.y; v[2] = (__bf16)wa.z; v[3] = (__bf16)wa.w;
            v[4] = (__bf16)wb.x; v[5] = (__bf16)wb.y; v[6] = (__bf16)wb.z; v[7] = (__bf16)wb.w;
            afr[at] = v;
            const float4 bi = *reinterpret_cast<const float4*>(pwB + at * 16 + (px >> 4) * 4);
            #pragma unroll
            for (int bt = 0; bt < 4; ++bt) {
                acc[at][bt][0] = bi.x; acc[at][bt][1] = bi.y;
                acc[at][bt][2] = bi.z; acc[at][bt][3] = bi.w;
            }
        }
        // 8 MFMAs: B = own-wave G (k-slices per lane)
        #pragma unroll
        for (int bt = 0; bt < 4; ++bt) {
            const int p2 = bt * 16 + (px & 15);
            const bf16x8 bfg = *reinterpret_cast<const bf16x8*>(
                &Gk[p2 * 4 + ((px >> 4) ^ (px & 3))]);
            #pragma unroll
            for (int at = 0; at < 2; ++at)
                acc[at][bt] = __builtin_amdgcn_mfma_f32_16x16x32_bf16(
                                  afr[at], bfg, acc[at][bt], 0, 0, 0);
        }
        __syncthreads();   // all waves done reading their G region

        // store pw result to zx exchange: [px][k*32 + j] bf16, chunk-swizzled
        #pragma unroll
        for (int at = 0; at < 2; ++at)
            #pragma unroll
            for (int bt = 0; bt < 4; ++bt) {
                const int p2  = bt * 16 + (px & 15);
                const int jj  = at * 16 + ((px >> 4) << 2);   // local out base (4 ch)
                const int ck  = k * 4 + (jj >> 3);
                const int sub = (jj >> 2) & 1;
                uint2 o;
                o.x = (unsigned)f2ubf(acc[at][bt][0]) | ((unsigned)f2ubf(acc[at][bt][1]) << 16);
                o.y = (unsigned)f2ubf(acc[at][bt][2]) | ((unsigned)f2ubf(acc[at][bt][3]) << 16);
                *reinterpret_cast<uint2*>(
                    reinterpret_cast<char*>(zx4) + p2 * 256 +
                    ((ck ^ (p2 & 15)) << 4) + sub * 8) = o;
            }
    }
    __syncthreads();

    // ---------- Phase 3a: wave s = z-segment; lane = pixel.
    // c5 + shuffle-interleave -> zx4 in final z layout ----------
    {
        const int s   = tid >> 6;          // segment 0..3 (wave-uniform)
        const int p3  = tid & 63;          // pixel
        const int py3 = p3 >> 3, px3 = p3 & 7;
        const int sw  = p3 & 15;
        const int klo = (s < 2) ? 1 : 3;
        const int khi = (s < 2) ? 0 : 2;
        const int cb  = (s & 1) * 2;

        const uint4 lo0 = zx4[p3 * 16 + ((klo * 4 + cb)     ^ sw)];
        const uint4 lo1 = zx4[p3 * 16 + ((klo * 4 + cb + 1) ^ sw)];
        const uint4 hi0 = zx4[p3 * 16 + ((khi * 4 + cb)     ^ sw)];
        const uint4 hi1 = zx4[p3 * 16 + ((khi * 4 + cb + 1) ^ sw)];
        __syncthreads();   // all pw-exchange reads done before z-layout overwrite

        float Flo[16], Fhi[16];
        unpack8(Flo,     lo0); unpack8(Flo + 8, lo1);
        unpack8(Fhi,     hi0); unpack8(Fhi + 8, hi1);

        // pre-shuffle channel bases: ob(k=1)=0, ob(k=3)=32, ob(k=0)=64, ob(k=2)=96
        const int obLo = (s < 2) ? 0  : 32;
        const int obHi = (s < 2) ? 64 : 96;
        const float* c5wL = rflp(c5w + (obLo + cb * 8) * 9);
        const float* c5bL = rflp(c5b +  obLo + cb * 8);
        const float* c5wH = rflp(c5w + (obHi + cb * 8) * 9);
        const float* c5bH = rflp(c5b +  obHi + cb * 8);
        #pragma unroll
        for (int i = 0; i < 16; ++i) { Flo[i] += c5bL[i]; Fhi[i] += c5bH[i]; }
        conv16(Flo, y_s4, c5wL, py3 + 1, px3 + 1, (obLo >> 3) + cb);
        conv16(Fhi, y_s4, c5wH, py3 + 1, px3 + 1, (obHi >> 3) + cb);

        // interleave (shuffle) + pack -> zx4 in z layout: chunk s*4+c of pixel p3
        #pragma unroll
        for (int c = 0; c < 4; ++c) {
            uint4 o;
            o.x = (unsigned)f2ubf(Flo[4*c+0]) | ((unsigned)f2ubf(Fhi[4*c+0]) << 16);
            o.y = (unsigned)f2ubf(Flo[4*c+1]) | ((unsigned)f2ubf(Fhi[4*c+1]) << 16);
            o.z = (unsigned)f2ubf(Flo[4*c+2]) | ((unsigned)f2ubf(Fhi[4*c+2]) << 16);
            o.w = (unsigned)f2ubf(Flo[4*c+3]) | ((unsigned)f2ubf(Fhi[4*c+3]) << 16);
            zx4[p3 * 16 + ((s * 4 + c) ^ sw)] = o;
        }
    }
    __syncthreads();

    // ---------- Phase 3b: coalesced z store + LN2 stats ----------
    {
        const int p  = tid >> 2;           // pixel 0..63
        const int q  = tid & 3;            // z segment
        const int sw = p & 15;

        uint4 o0 = zx4[p * 16 + ((q * 4 + 0) ^ sw)];
        uint4 o1 = zx4[p * 16 + ((q * 4 + 1) ^ sw)];
        uint4 o2 = zx4[p * 16 + ((q * 4 + 2) ^ sw)];
        uint4 o3 = zx4[p * 16 + ((q * 4 + 3) ^ sw)];

        const int gh = h0 + (p >> 3), gw = w0 + (p & 7);
        unsigned int* zp = zout + ((size_t)b * HWsz + (size_t)gh * W_ + gw) * 64 + q * 16;
        *reinterpret_cast<uint4*>(zp + 0)  = o0;
        *reinterpret_cast<uint4*>(zp + 4)  = o1;
        *reinterpret_cast<uint4*>(zp + 8)  = o2;
        *reinterpret_cast<uint4*>(zp + 12) = o3;

        // stats over the 32 channels this thread stored
        float s1 = 0.f, s2 = 0.f;
        #define ACC(wrd) { const float fl = ubf2f((unsigned short)((wrd) & 0xffffu)); \
                           const float fh = ubf2f((unsigned short)((wrd) >> 16));     \
                           s1 += fl + fh; s2 += fl * fl + fh * fh; }
        ACC(o0.x) ACC(o0.y) ACC(o0.z) ACC(o0.w)
        ACC(o1.x) ACC(o1.y) ACC(o1.z) ACC(o1.w)
        ACC(o2.x) ACC(o2.y) ACC(o2.z) ACC(o2.w)
        ACC(o3.x) ACC(o3.y) ACC(o3.z) ACC(o3.w)
        #undef ACC

        s1 += __shfl_xor(s1, 1); s1 += __shfl_xor(s1, 2);
        s2 += __shfl_xor(s2, 1); s2 += __shfl_xor(s2, 2);
        if (q == 0) {
            const float mu  = s1 * (1.0f / 128.0f);
            const float var = s2 * (1.0f / 128.0f) - mu * mu;
            st2[(size_t)b * HWsz + (size_t)gh * W_ + gw] = make_float2(mu, rsqrtf(var + 1e-6f));
        }
    }
}

// =====================================================================
// Kernel B: stage LN2(z)-halo in LDS (bf16, swizzled NHWC) ->
//           dw3 + GELU from LDS -> g_s -> 128x128 pointwise via MFMA
// =====================================================================
__global__ __launch_bounds__(256, 2)
void kernelB(const unsigned short* __restrict__ z, const float2* __restrict__ st2,
             const float* __restrict__ n2w, const float* __restrict__ n2b,
             const float* __restrict__ dwT, const float* __restrict__ dwB,
             const float* __restrict__ pwW, const float* __restrict__ pwB,
             float* __restrict__ out)
{
    __shared__ uint4 w_s4[NHALO_B * 16];                 // 46,080 B
    __shared__ unsigned short g_s[PBH * PBW * GPITCH];   // 34,816 B

    const int tid  = threadIdx.x;
    const int lane = tid & 63;
    const int wv   = tid >> 6;
    const int b    = blockIdx.z;
    const int h0   = blockIdx.y * PBH;
    const int w0   = blockIdx.x * PBW;

    // ---------------- Phase S: stage LN2-normalized halo into w_s4 ----------------
    {
        const int ch = tid & 15;          // 16B chunk (8 channels)
        const int pb = tid >> 4;          // 0..15
        float nw[8], nb[8];
        #pragma unroll
        for (int j = 0; j < 8; ++j) {
            nw[j] = n2w[ch * 8 + j];
            nb[j] = n2b[ch * 8 + j];
        }
        #pragma unroll
        for (int it = 0; it < 12; ++it) {
            const int p = it * 16 + pb;   // halo pixel 0..179
            if (p < NHALO_B) {
                const int ph = p / HBW, pw2 = p - ph * HBW;
                const int gy = h0 - 1 + ph, gx = w0 - 1 + pw2;
                uint4 o = make_uint4(0u, 0u, 0u, 0u);
                if ((unsigned)gy < (unsigned)H_ && (unsigned)gx < (unsigned)W_) {
                    const size_t pp = (size_t)b * HWsz + (size_t)gy * W_ + gx;
                    const uint4 zv = *reinterpret_cast<const uint4*>(z + pp * Cch + ch * 8);
                    const float2 st = st2[pp];
                    const float f0 = (ubf2f((unsigned short)(zv.x & 0xffffu)) - st.x) * st.y * nw[0] + nb[0];
                    const float f1 = (ubf2f((unsigned short)(zv.x >> 16))     - st.x) * st.y * nw[1] + nb[1];
                    const float f2 = (ubf2f((unsigned short)(zv.y & 0xffffu)) - st.x) * st.y * nw[2] + nb[2];
                    const float f3 = (ubf2f((unsigned short)(zv.y >> 16))     - st.x) * st.y * nw[3] + nb[3];
                    const float f4 = (ubf2f((unsigned short)(zv.z & 0xffffu)) - st.x) * st.y * nw[4] + nb[4];
                    const float f5 = (ubf2f((unsigned short)(zv.z >> 16))     - st.x) * st.y * nw[5] + nb[5];
                    const float f6 = (ubf2f((unsigned short)(zv.w & 0xffffu)) - st.x) * st.y * nw[6] + nb[6];
                    const float f7 = (ubf2f((unsigned short)(zv.w >> 16))     - st.x) * st.y * nw[7] + nb[7];
                    o.x = (unsigned)f2ubf(f0) | ((unsigned)f2ubf(f1) << 16);
                    o.y = (unsigned)f2ubf(f2) | ((unsigned)f2ubf(f3) << 16);
                    o.z = (unsigned)f2ubf(f4) | ((unsigned)f2ubf(f5) << 16);
                    o.w = (unsigned)f2ubf(f6) | ((unsigned)f2ubf(f7) << 16);
                }
                w_s4[p * 16 + (ch ^ (p & 15))] = o;
            }
        }
    }
    __syncthreads();

    // ---------------- Phase L: dw3 + GELU from LDS -> g_s (bf16) ----------------
    {
        const int cc = lane & 15;          // channel chunk (8 ch)
        const int sl = lane >> 4;          // 0..3
        const int s  = wv * 4 + sl;        // col in patch 0..15
        const int cbase = cc * 8;

        float db[8];
        float wt[9][8];
        #pragma unroll
        for (int j = 0; j < 8; ++j) db[j] = dwB[cbase + j];
        #pragma unroll
        for (int t = 0; t < 9; ++t)
            #pragma unroll
            for (int j = 0; j < 8; ++j)
                wt[t][j] = dwT[t * Cch + cbase + j];

        for (int r = 0; r < PBH; ++r) {
            float a[8];
            #pragma unroll
            for (int j = 0; j < 8; ++j) a[j] = db[j];

            #pragma unroll
            for (int dy = 0; dy < 3; ++dy)
                #pragma unroll
                for (int dx = 0; dx < 3; ++dx) {
                    const int tap = dy * 3 + dx;
                    const int q = (r + dy) * HBW + (s + dx);
                    const uint4 t4 = w_s4[q * 16 + (cc ^ (q & 15))];
                    a[0] = fmaf(wt[tap][0], ubf2f((unsigned short)(t4.x & 0xffffu)), a[0]);
                    a[1] = fmaf(wt[tap][1], ubf2f((unsigned short)(t4.x >> 16)),     a[1]);
                    a[2] = fmaf(wt[tap][2], ubf2f((unsigned short)(t4.y & 0xffffu)), a[2]);
                    a[3] = fmaf(wt[tap][3], ubf2f((unsigned short)(t4.y >> 16)),     a[3]);
                    a[4] = fmaf(wt[tap][4], ubf2f((unsigned short)(t4.z & 0xffffu)), a[4]);
                    a[5] = fmaf(wt[tap][5], ubf2f((unsigned short)(t4.z >> 16)),     a[5]);
                    a[6] = fmaf(wt[tap][6], ubf2f((unsigned short)(t4.w & 0xffffu)), a[6]);
                    a[7] = fmaf(wt[tap][7], ubf2f((unsigned short)(t4.w >> 16)),     a[7]);
                }

            unsigned int pk[4];
            #pragma unroll
            for (int q = 0; q < 4; ++q) {
                const unsigned short lo = f2ubf(gelu_exact(a[2*q]));
                const unsigned short hi = f2ubf(gelu_exact(a[2*q+1]));
                pk[q] = (unsigned int)lo | ((unsigned int)hi << 16);
            }
            const int row = r * PBW + s;
            const int boff = row * (GPITCH * 2) + ((cbase * 2) ^ ((row & 3) << 4));
            *reinterpret_cast<uint4*>(reinterpret_cast<char*>(g_s) + boff) =
                make_uint4(pk[0], pk[1], pk[2], pk[3]);
        }
    }
    __syncthreads();

    // ---------------- Phase P: 128x128 pointwise via MFMA ----------------
    {
        const int ll = lane & 15;
        const int lh = lane >> 4;

        bf16x8 bfr[2][4];
        float  pb[2];
        #pragma unroll
        for (int t2 = 0; t2 < 2; ++t2) {
            const int o = (wv * 2 + t2) * 16 + ll;
            pb[t2] = pwB[o];
            #pragma unroll
            for (int kt = 0; kt < 4; ++kt) {
                const float* wp = pwW + (size_t)o * Cch + kt * 32 + lh * 8;
                bf16x8 vv;
                #pragma unroll
                for (int j = 0; j < 8; ++j) vv[j] = (__bf16)wp[j];
                bfr[t2][kt] = vv;
            }
        }

        #pragma unroll
        for (int r = 0; r < PBH; ++r) {
            const int row = r * PBW + ll;
            bf16x8 af[4];
            #pragma unroll
            for (int kt = 0; kt < 4; ++kt) {
                const int boff = row * (GPITCH * 2) + ((kt * 64 + lh * 16) ^ ((row & 3) << 4));
                af[kt] = *reinterpret_cast<const bf16x8*>(
                            reinterpret_cast<const char*>(g_s) + boff);
            }
            #pragma unroll
            for (int t2 = 0; t2 < 2; ++t2) {
                f32x4 acc = {0.f, 0.f, 0.f, 0.f};
                #pragma unroll
                for (int kt = 0; kt < 4; ++kt)
                    acc = __builtin_amdgcn_mfma_f32_16x16x32_bf16(af[kt], bfr[t2][kt], acc, 0, 0, 0);
                const int o = (wv * 2 + t2) * 16 + ll;
                float4 res = make_float4(acc[0] + pb[t2], acc[1] + pb[t2],
                                         acc[2] + pb[t2], acc[3] + pb[t2]);
                *reinterpret_cast<float4*>(
                    out + ((size_t)b * Cch + o) * HWsz + (size_t)(h0 + r) * W_ + w0 + lh * 4) = res;
            }
        }
    }
}

// =====================================================================
extern "C" void kernel_launch(void* const* d_in, const int* in_sizes, int n_in,
                              void* d_out, int out_size, void* d_ws, size_t ws_size,
                              hipStream_t stream)
{
    const float* x    = (const float*)d_in[0];
    const float* n1w  = (const float*)d_in[1];
    const float* n1b  = (const float*)d_in[2];
    const float* n2w  = (const float*)d_in[3];
    const float* n2b  = (const float*)d_in[4];
    const float* c5w  = (const float*)d_in[5];
    const float* c5b  = (const float*)d_in[6];
    const float* ldww = (const float*)d_in[7];
    const float* ldwb = (const float*)d_in[8];
    const float* lpww = (const float*)d_in[9];
    const float* lpwb = (const float*)d_in[10];
    const float* s1dw = (const float*)d_in[11];
    const float* s1db = (const float*)d_in[12];
    const float* s1pw = (const float*)d_in[13];
    const float* s1pb = (const float*)d_in[14];
    const float* s2dw = (const float*)d_in[15];
    const float* s2db = (const float*)d_in[16];
    const float* s2pw = (const float*)d_in[17];
    const float* s2pb = (const float*)d_in[18];
    const float* s3dw = (const float*)d_in[19];
    const float* s3db = (const float*)d_in[20];
    const float* s3pw = (const float*)d_in[21];
    const float* s3pb = (const float*)d_in[22];
    const float* s4dw = (const float*)d_in[23];
    const float* s4db = (const float*)d_in[24];
    const float* s4pw = (const float*)d_in[25];
    const float* s4pb = (const float*)d_in[26];

    // workspace layout: y (bf16 NHWC) | z (bf16 NHWC) | st2 (float2) | dwT
    const size_t yBytes  = (size_t)8 * Cch * HWsz * sizeof(unsigned short); // 102,760,448
    const size_t zBytes  = yBytes;                                          // 102,760,448
    const size_t stBytes = (size_t)8 * HWsz * sizeof(float2);               //   3,211,264
    unsigned int*   y_u32 = (unsigned int*)d_ws;
    unsigned short* y_u16 = (unsigned short*)d_ws;
    unsigned int*   z_u32 = (unsigned int*)((char*)d_ws + yBytes);
    unsigned short* z_u16 = (unsigned short*)((char*)d_ws + yBytes);
    float2* st2 = (float2*)((char*)d_ws + yBytes + zBytes);
    float*  dwT = (float*)((char*)d_ws + yBytes + zBytes + stBytes);

    prep<<<dim3(5), 256, 0, stream>>>(ldww, dwT);
    lnT<<<dim3(HWsz / TPX, 8), 256, 0, stream>>>(x, n1w, n1b, y_u32);

    kernelA<<<dim3(W_ / TAW, H_ / TAH, 8), 256, 0, stream>>>(
        y_u16, c5w, c5b,
        s1dw, s1db, s1pw, s1pb,
        s2dw, s2db, s2pw, s2pb,
        s3dw, s3db, s3pw, s3pb,
        s4dw, s4db, s4pw, s4pb, z_u32, st2);

    kernelB<<<dim3(W_ / PBW, H_ / PBH, 8), 256, 0, stream>>>(
        z_u16, st2, n2w, n2b, dwT, ldwb, lpww, lpwb, (float*)d_out);
}

// Round 22
// 433.324 us; speedup vs baseline: 1.6115x; 1.0014x over previous
//
#include <hip/hip_runtime.h>
#include <hip/hip_bf16.h>
#include <math.h>

#define H_   224
#define W_   224
#define HWsz 50176      // 224*224
#define Cch  128

// Kernel A: out tile 8x8, halo 2 -> 12x12
#define TAH 8
#define TAW 8
#define HAH 12
#define HAW 12
#define NHALO_A (HAH*HAW)   // 144  (row 144 = dedicated zero pixel)

// Kernel B: patch 8 rows x 16 cols, halo 1 -> 10x18
#define PBH 8
#define PBW 16
#define HBH 10
#define HBW 18
#define NHALO_B (HBH*HBW)   // 180
#define GPITCH 136          // g_s row pitch in bf16 units (272 B)

// lnT: pixels per block
#define TPX 64

typedef __bf16 bf16x8 __attribute__((ext_vector_type(8)));
typedef float  f32x4  __attribute__((ext_vector_type(4)));

__device__ __forceinline__ float bf2f(__hip_bfloat16 v) { return __bfloat162float(v); }
__device__ __forceinline__ __hip_bfloat16 f2bf(float v) { return __float2bfloat16(v); }
__device__ __forceinline__ float ubf2f(unsigned short u) {
    unsigned x = ((unsigned)u) << 16; return __int_as_float((int)x);
}
__device__ __forceinline__ unsigned short f2ubf(float f) {
    __hip_bfloat16 h = __float2bfloat16(f);
    return *reinterpret_cast<unsigned short*>(&h);
}
// exact GELU (erf) — the fast tanh variant failed post-timing revalidation
// in rounds 14/15; keep the proven-deterministic path.
__device__ __forceinline__ float gelu_exact(float x) {
    return 0.5f * x * (1.0f + erff(x * 0.70710678118654752440f));
}
// readfirstlane a wave-uniform pointer into SGPRs so weight reads become s_loads
__device__ __forceinline__ const float* rflp(const float* p) {
    unsigned long long v = (unsigned long long)p;
    unsigned lo = __builtin_amdgcn_readfirstlane((unsigned)v);
    unsigned hi = __builtin_amdgcn_readfirstlane((unsigned)(v >> 32));
    return (const float*)(((unsigned long long)hi << 32) | lo);
}
__device__ __forceinline__ void unpack8(float* F, uint4 v) {
    F[0] = ubf2f((unsigned short)(v.x & 0xffffu)); F[1] = ubf2f((unsigned short)(v.x >> 16));
    F[2] = ubf2f((unsigned short)(v.y & 0xffffu)); F[3] = ubf2f((unsigned short)(v.y >> 16));
    F[4] = ubf2f((unsigned short)(v.z & 0xffffu)); F[5] = ubf2f((unsigned short)(v.z >> 16));
    F[6] = ubf2f((unsigned short)(v.w & 0xffffu)); F[7] = ubf2f((unsigned short)(v.w >> 16));
}

// =====================================================================
// prep: transpose ldw depthwise weights to dwT[tap][c]
// =====================================================================
__global__ __launch_bounds__(256)
void prep(const float* __restrict__ ldww, float* __restrict__ dwT)
{
    const int i = blockIdx.x * 256 + threadIdx.x;
    if (i < 9 * Cch) {
        const int t = i >> 7, c = i & 127;
        dwT[i] = ldww[c * 9 + t];
    }
}

// =====================================================================
// lnT: LN1 (stats + normalize) + NCHW->NHWC transpose, bf16 out
// =====================================================================
__global__ __launch_bounds__(256, 4)
void lnT(const float* __restrict__ x,
         const float* __restrict__ n1w, const float* __restrict__ n1b,
         unsigned int* __restrict__ y)
{
    __shared__ float xs[TPX][Cch + 1];      // 33,024 B
    __shared__ float rs_[4][TPX], rss_[4][TPX];
    __shared__ float2 st_s[TPX];

    const int t   = threadIdx.x;
    const int b   = blockIdx.y;
    const int sp0 = blockIdx.x * TPX;

    // phase a: coalesced load, transpose into LDS
    {
        const int lane = t & 63, wv = t >> 6;
        const float* xb = x + (size_t)b * Cch * HWsz + sp0 + lane;
        #pragma unroll 8
        for (int k = 0; k < 32; ++k) {
            const int c = wv * 32 + k;
            xs[lane][c] = xb[(size_t)c * HWsz];
        }
    }
    __syncthreads();

    // phase b: per-pixel stats (4 threads per pixel)
    {
        const int p = t & 63, q = t >> 6;
        float s = 0.f, ss = 0.f;
        #pragma unroll
        for (int k = 0; k < 32; ++k) {
            const float v = xs[p][q * 32 + k];
            s += v; ss += v * v;
        }
        rs_[q][p] = s; rss_[q][p] = ss;
    }
    __syncthreads();
    if (t < TPX) {
        const float S  = rs_[0][t] + rs_[1][t] + rs_[2][t] + rs_[3][t];
        const float SS = rss_[0][t] + rss_[1][t] + rss_[2][t] + rss_[3][t];
        const float mu  = S * (1.0f / 128.0f);
        const float var = SS * (1.0f / 128.0f) - mu * mu;
        st_s[t] = make_float2(mu, rsqrtf(var + 1e-6f));
    }
    __syncthreads();

    // phase c: normalize + pack bf16 + coalesced NHWC store
    {
        const int ch = t & 15;          // 16B chunk (8 channels)
        const int pb = t >> 4;          // 0..15
        float w8[8], b8[8];
        #pragma unroll
        for (int j = 0; j < 8; ++j) {
            w8[j] = n1w[ch * 8 + j];
            b8[j] = n1b[ch * 8 + j];
        }
        #pragma unroll
        for (int it = 0; it < 4; ++it) {
            const int p = it * 16 + pb;
            const float2 st = st_s[p];
            unsigned int pk[4];
            #pragma unroll
            for (int u = 0; u < 4; ++u) {
                const int c0 = ch * 8 + u * 2;
                const float v0 = (xs[p][c0]     - st.x) * st.y * w8[u*2]   + b8[u*2];
                const float v1 = (xs[p][c0 + 1] - st.x) * st.y * w8[u*2+1] + b8[u*2+1];
                pk[u] = (unsigned int)f2ubf(v0) | ((unsigned int)f2ubf(v1) << 16);
            }
            *reinterpret_cast<uint4*>(y + ((size_t)b * HWsz + sp0 + p) * 64 + ch * 4) =
                make_uint4(pk[0], pk[1], pk[2], pk[3]);
        }
    }
}

// =====================================================================
// conv_taps: accumulate 9 taps x 32 channels from swizzled NHWC LDS.
// w9 MUST be an SGPR (readfirstlane'd) pointer -> weights are s_loads.
// mask handled by redirecting the tap address to the zero row (144)
// =====================================================================
__device__ __forceinline__ void conv_taps(
    float* __restrict__ G, const uint4* __restrict__ ys4,
    const float* __restrict__ w9,
    int rb, int cb, int chunkBase,
    const bool* rowOK, const bool* colOK, bool useMask)
{
    #pragma unroll
    for (int t3 = 0; t3 < 3; ++t3)
        #pragma unroll
        for (int t4 = 0; t4 < 3; ++t4) {
            const int tap = t3 * 3 + t4;
            int q = (rb + t3) * HAW + (cb + t4);
            if (useMask && !(rowOK[t3] && colOK[t4])) q = NHALO_A;  // zero row
            const char* base = reinterpret_cast<const char*>(ys4) + q * 256;
            const int sw = q & 15;
            #pragma unroll
            for (int u = 0; u < 4; ++u) {
                const uint4 t = *reinterpret_cast<const uint4*>(
                                    base + (((chunkBase + u) ^ sw) << 4));
                const int i0 = u * 8;
                G[i0+0] = fmaf(w9[(i0+0)*9+tap], ubf2f((unsigned short)(t.x & 0xffffu)), G[i0+0]);
                G[i0+1] = fmaf(w9[(i0+1)*9+tap], ubf2f((unsigned short)(t.x >> 16)),     G[i0+1]);
                G[i0+2] = fmaf(w9[(i0+2)*9+tap], ubf2f((unsigned short)(t.y & 0xffffu)), G[i0+2]);
                G[i0+3] = fmaf(w9[(i0+3)*9+tap], ubf2f((unsigned short)(t.y >> 16)),     G[i0+3]);
                G[i0+4] = fmaf(w9[(i0+4)*9+tap], ubf2f((unsigned short)(t.z & 0xffffu)), G[i0+4]);
                G[i0+5] = fmaf(w9[(i0+5)*9+tap], ubf2f((unsigned short)(t.z >> 16)),     G[i0+5]);
                G[i0+6] = fmaf(w9[(i0+6)*9+tap], ubf2f((unsigned short)(t.w & 0xffffu)), G[i0+6]);
                G[i0+7] = fmaf(w9[(i0+7)*9+tap], ubf2f((unsigned short)(t.w >> 16)),     G[i0+7]);
            }
        }
}

// conv16: same, but 16 channels (2 chunks), no mask (c5 path)
__device__ __forceinline__ void conv16(
    float* __restrict__ F, const uint4* __restrict__ ys4,
    const float* __restrict__ w9,
    int rb, int cbq, int chunkBase)
{
    #pragma unroll
    for (int t3 = 0; t3 < 3; ++t3)
        #pragma unroll
        for (int t4 = 0; t4 < 3; ++t4) {
            const int tap = t3 * 3 + t4;
            const int q = (rb + t3) * HAW + (cbq + t4);
            const char* base = reinterpret_cast<const char*>(ys4) + q * 256;
            const int sw = q & 15;
            #pragma unroll
            for (int u = 0; u < 2; ++u) {
                const uint4 t = *reinterpret_cast<const uint4*>(
                                    base + (((chunkBase + u) ^ sw) << 4));
                const int i0 = u * 8;
                F[i0+0] = fmaf(w9[(i0+0)*9+tap], ubf2f((unsigned short)(t.x & 0xffffu)), F[i0+0]);
                F[i0+1] = fmaf(w9[(i0+1)*9+tap], ubf2f((unsigned short)(t.x >> 16)),     F[i0+1]);
                F[i0+2] = fmaf(w9[(i0+2)*9+tap], ubf2f((unsigned short)(t.y & 0xffffu)), F[i0+2]);
                F[i0+3] = fmaf(w9[(i0+3)*9+tap], ubf2f((unsigned short)(t.y >> 16)),     F[i0+3]);
                F[i0+4] = fmaf(w9[(i0+4)*9+tap], ubf2f((unsigned short)(t.z & 0xffffu)), F[i0+4]);
                F[i0+5] = fmaf(w9[(i0+5)*9+tap], ubf2f((unsigned short)(t.z >> 16)),     F[i0+5]);
                F[i0+6] = fmaf(w9[(i0+6)*9+tap], ubf2f((unsigned short)(t.w & 0xffffu)), F[i0+6]);
                F[i0+7] = fmaf(w9[(i0+7)*9+tap], ubf2f((unsigned short)(t.w >> 16)),     F[i0+7]);
            }
        }
}

// =====================================================================
// Kernel A (8x8 tile, wave=chunk): y(NHWC bf16) -> 4 shift branches
// (dw3+GELU in VALU, pw32 via MFMA) -> zx exchange -> phase 3a: c5 +
// interleave back to zx -> phase 3b: coalesced z store + LN2 stats
// =====================================================================
__global__ __launch_bounds__(256, 3)
void kernelA(const unsigned short* __restrict__ y,
             const float* __restrict__ c5w, const float* __restrict__ c5b,
             const float* __restrict__ s1dw, const float* __restrict__ s1db,
             const float* __restrict__ s1pw, const float* __restrict__ s1pb,
             const float* __restrict__ s2dw, const float* __restrict__ s2db,
             const float* __restrict__ s2pw, const float* __restrict__ s2pb,
             const float* __restrict__ s3dw, const float* __restrict__ s3db,
             const float* __restrict__ s3pw, const float* __restrict__ s3pb,
             const float* __restrict__ s4dw, const float* __restrict__ s4db,
             const float* __restrict__ s4pw, const float* __restrict__ s4pb,
             unsigned int* __restrict__ zout, float2* __restrict__ st2)
{
    __shared__ uint4 y_s4[(NHALO_A + 1) * 16];   // 37,120 B (incl zero row)
    __shared__ uint4 zx4[TAH * TAW * 16];        // 16,384 B: G-LDS -> pw-exch -> z-exch

    const int tid = threadIdx.x;
    const int b   = blockIdx.z;
    const int h0  = blockIdx.y * TAH;
    const int w0  = blockIdx.x * TAW;

    // ---------- Phase 1: coalesced NHWC load -> swizzled b128 LDS store ----------
    {
        const int ch = tid & 15;          // 16B chunk (8 channels)
        const int pb = tid >> 4;          // 0..15
        #pragma unroll
        for (int it = 0; it < 9; ++it) {
            const int p  = it * 16 + pb;  // halo pixel index 0..143
            const int ph = p / HAW, pw2 = p - ph * HAW;
            const int gy = h0 - 2 + ph, gx = w0 - 2 + pw2;
            uint4 v = make_uint4(0u, 0u, 0u, 0u);
            if ((unsigned)gy < (unsigned)H_ && (unsigned)gx < (unsigned)W_)
                v = *reinterpret_cast<const uint4*>(
                    y + ((size_t)b * HWsz + (size_t)gy * W_ + gx) * Cch + ch * 8);
            y_s4[p * 16 + (ch ^ pb)] = v;
        }
        if (tid < 16) y_s4[NHALO_A * 16 + tid] = make_uint4(0u, 0u, 0u, 0u);
    }
    __syncthreads();

    // ---------- Phase 2: wave k: dw3+GELU (VALU), pw32 (MFMA) ----------
    {
        const int px  = tid & 63;          // pixel in 8x8 tile (= lane)
        const int k   = tid >> 6;          // chunk id, wave-uniform
        const int py  = px >> 3, pxx = px & 7;
        const int gh  = h0 + py, gw = w0 + pxx;

        bool rowOK[3], colOK[3];
        #pragma unroll
        for (int t = 0; t < 3; ++t) {
            rowOK[t] = (gh - 1 + t >= 0) && (gh - 1 + t < H_);
            colOK[t] = (gw - 1 + t >= 0) && (gw - 1 + t < W_);
        }

        // chunk table: k=0:s1 sh(1,1) | k=1:s2 sh(-1,1) | k=2:s3 sh(-1,-1) | k=3:s4 sh(1,-1)
        const float* dwW = rflp(k == 0 ? s1dw : k == 1 ? s2dw : k == 2 ? s3dw : s4dw);
        const float* dwB = rflp(k == 0 ? s1db : k == 1 ? s2db : k == 2 ? s3db : s4db);
        const float* pwW = rflp(k == 0 ? s1pw : k == 1 ? s2pw : k == 2 ? s3pw : s4pw);
        const float* pwB = rflp(k == 0 ? s1pb : k == 1 ? s2pb : k == 2 ? s3pb : s4pb);
        const int shh = (k == 0 || k == 3) ? 1 : -1;
        const int shw = (k <= 1) ? 1 : -1;

        float G[32];
        #pragma unroll
        for (int i = 0; i < 32; ++i) G[i] = dwB[i];
        conv_taps(G, y_s4, dwW, py + 1 - shh, pxx + 1 - shw, k * 4, rowOK, colOK, true);
        #pragma unroll
        for (int i = 0; i < 32; ++i) G[i] = gelu_exact(G[i]);

        // G -> wave-private LDS region (bf16, 16B-chunk swizzled by px&3)
        uint4* Gk = zx4 + k * 256;
        #pragma unroll
        for (int c = 0; c < 4; ++c) {
            uint4 o;
            o.x = (unsigned)f2ubf(G[c*8+0]) | ((unsigned)f2ubf(G[c*8+1]) << 16);
            o.y = (unsigned)f2ubf(G[c*8+2]) | ((unsigned)f2ubf(G[c*8+3]) << 16);
            o.z = (unsigned)f2ubf(G[c*8+4]) | ((unsigned)f2ubf(G[c*8+5]) << 16);
            o.w = (unsigned)f2ubf(G[c*8+6]) | ((unsigned)f2ubf(G[c*8+7]) << 16);
            Gk[px * 4 + (c ^ (px & 3))] = o;
        }
        __builtin_amdgcn_sched_barrier(0);   // keep ds_reads after ds_writes

        // A-fragments (pwW -> bf16) and bias-initialized accumulators.
        // D[out][px]: lane holds col=px=(l&15), row=out=(l>>4)*4+r.
        bf16x8 afr[2];
        f32x4  acc[2][4];
        #pragma unroll
        for (int at = 0; at < 2; ++at) {
            const float* wp = pwW + (at * 16 + (px & 15)) * 32 + (px >> 4) * 8;
            const float4 wa = *reinterpret_cast<const float4*>(wp);
            const float4 wb = *reinterpret_cast<const float4*>(wp + 4);
            bf16x8 v;
            v[0] = (__bf16)wa.x; v[1] = (__bf16)wa.y; v[2] = (__bf16)wa.z; v[3] = (__bf16)wa.w;
            v[4] = (__bf16)wb.x; v[5] = (__bf16)wb.y; v[6] = (__bf16)wb.z; v[7] = (__bf16)wb.w;
            afr[at] = v;
            const float4 bi = *reinterpret_cast<const float4*>(pwB + at * 16 + (px >> 4) * 4);
            #pragma unroll
            for (int bt = 0; bt < 4; ++bt) {
                acc[at][bt][0] = bi.x; acc[at][bt][1] = bi.y;
                acc[at][bt][2] = bi.z; acc[at][bt][3] = bi.w;
            }
        }
        // 8 MFMAs: B = own-wave G (k-slices per lane)
        #pragma unroll
        for (int bt = 0; bt < 4; ++bt) {
            const int p2 = bt * 16 + (px & 15);
            const bf16x8 bfg = *reinterpret_cast<const bf16x8*>(
                &Gk[p2 * 4 + ((px >> 4) ^ (px & 3))]);
            #pragma unroll
            for (int at = 0; at < 2; ++at)
                acc[at][bt] = __builtin_amdgcn_mfma_f32_16x16x32_bf16(
                                  afr[at], bfg, acc[at][bt], 0, 0, 0);
        }
        __syncthreads();   // all waves done reading their G region

        // store pw result to zx exchange: [px][k*32 + j] bf16, chunk-swizzled
        #pragma unroll
        for (int at = 0; at < 2; ++at)
            #pragma unroll
            for (int bt = 0; bt < 4; ++bt) {
                const int p2  = bt * 16 + (px & 15);
                const int jj  = at * 16 + ((px >> 4) << 2);   // local out base (4 ch)
                const int ck  = k * 4 + (jj >> 3);
                const int sub = (jj >> 2) & 1;
                uint2 o;
                o.x = (unsigned)f2ubf(acc[at][bt][0]) | ((unsigned)f2ubf(acc[at][bt][1]) << 16);
                o.y = (unsigned)f2ubf(acc[at][bt][2]) | ((unsigned)f2ubf(acc[at][bt][3]) << 16);
                *reinterpret_cast<uint2*>(
                    reinterpret_cast<char*>(zx4) + p2 * 256 +
                    ((ck ^ (p2 & 15)) << 4) + sub * 8) = o;
            }
    }
    __syncthreads();

    // ---------- Phase 3a: wave s = z-segment; lane = pixel.
    // c5 + shuffle-interleave -> zx4 in final z layout ----------
    {
        const int s   = tid >> 6;          // segment 0..3 (wave-uniform)
        const int p3  = tid & 63;          // pixel
        const int py3 = p3 >> 3, px3 = p3 & 7;
        const int sw  = p3 & 15;
        const int klo = (s < 2) ? 1 : 3;
        const int khi = (s < 2) ? 0 : 2;
        const int cb  = (s & 1) * 2;

        const uint4 lo0 = zx4[p3 * 16 + ((klo * 4 + cb)     ^ sw)];
        const uint4 lo1 = zx4[p3 * 16 + ((klo * 4 + cb + 1) ^ sw)];
        const uint4 hi0 = zx4[p3 * 16 + ((khi * 4 + cb)     ^ sw)];
        const uint4 hi1 = zx4[p3 * 16 + ((khi * 4 + cb + 1) ^ sw)];
        __syncthreads();   // all pw-exchange reads done before z-layout overwrite

        float Flo[16], Fhi[16];
        unpack8(Flo,     lo0); unpack8(Flo + 8, lo1);
        unpack8(Fhi,     hi0); unpack8(Fhi + 8, hi1);

        // pre-shuffle channel bases: ob(k=1)=0, ob(k=3)=32, ob(k=0)=64, ob(k=2)=96
        const int obLo = (s < 2) ? 0  : 32;
        const int obHi = (s < 2) ? 64 : 96;
        const float* c5wL = rflp(c5w + (obLo + cb * 8) * 9);
        const float* c5bL = rflp(c5b +  obLo + cb * 8);
        const float* c5wH = rflp(c5w + (obHi + cb * 8) * 9);
        const float* c5bH = rflp(c5b +  obHi + cb * 8);
        #pragma unroll
        for (int i = 0; i < 16; ++i) { Flo[i] += c5bL[i]; Fhi[i] += c5bH[i]; }
        conv16(Flo, y_s4, c5wL, py3 + 1, px3 + 1, (obLo >> 3) + cb);
        conv16(Fhi, y_s4, c5wH, py3 + 1, px3 + 1, (obHi >> 3) + cb);

        // interleave (shuffle) + pack -> zx4 in z layout: chunk s*4+c of pixel p3
        #pragma unroll
        for (int c = 0; c < 4; ++c) {
            uint4 o;
            o.x = (unsigned)f2ubf(Flo[4*c+0]) | ((unsigned)f2ubf(Fhi[4*c+0]) << 16);
            o.y = (unsigned)f2ubf(Flo[4*c+1]) | ((unsigned)f2ubf(Fhi[4*c+1]) << 16);
            o.z = (unsigned)f2ubf(Flo[4*c+2]) | ((unsigned)f2ubf(Fhi[4*c+2]) << 16);
            o.w = (unsigned)f2ubf(Flo[4*c+3]) | ((unsigned)f2ubf(Fhi[4*c+3]) << 16);
            zx4[p3 * 16 + ((s * 4 + c) ^ sw)] = o;
        }
    }
    __syncthreads();

    // ---------- Phase 3b: coalesced z store + LN2 stats ----------
    {
        const int p  = tid >> 2;           // pixel 0..63
        const int q  = tid & 3;            // z segment
        const int sw = p & 15;

        uint4 o0 = zx4[p * 16 + ((q * 4 + 0) ^ sw)];
        uint4 o1 = zx4[p * 16 + ((q * 4 + 1) ^ sw)];
        uint4 o2 = zx4[p * 16 + ((q * 4 + 2) ^ sw)];
        uint4 o3 = zx4[p * 16 + ((q * 4 + 3) ^ sw)];

        const int gh = h0 + (p >> 3), gw = w0 + (p & 7);
        unsigned int* zp = zout + ((size_t)b * HWsz + (size_t)gh * W_ + gw) * 64 + q * 16;
        *reinterpret_cast<uint4*>(zp + 0)  = o0;
        *reinterpret_cast<uint4*>(zp + 4)  = o1;
        *reinterpret_cast<uint4*>(zp + 8)  = o2;
        *reinterpret_cast<uint4*>(zp + 12) = o3;

        // stats over the 32 channels this thread stored
        float s1 = 0.f, s2 = 0.f;
        #define ACC(wrd) { const float fl = ubf2f((unsigned short)((wrd) & 0xffffu)); \
                           const float fh = ubf2f((unsigned short)((wrd) >> 16));     \
                           s1 += fl + fh; s2 += fl * fl + fh * fh; }
        ACC(o0.x) ACC(o0.y) ACC(o0.z) ACC(o0.w)
        ACC(o1.x) ACC(o1.y) ACC(o1.z) ACC(o1.w)
        ACC(o2.x) ACC(o2.y) ACC(o2.z) ACC(o2.w)
        ACC(o3.x) ACC(o3.y) ACC(o3.z) ACC(o3.w)
        #undef ACC

        s1 += __shfl_xor(s1, 1); s1 += __shfl_xor(s1, 2);
        s2 += __shfl_xor(s2, 1); s2 += __shfl_xor(s2, 2);
        if (q == 0) {
            const float mu  = s1 * (1.0f / 128.0f);
            const float var = s2 * (1.0f / 128.0f) - mu * mu;
            st2[(size_t)b * HWsz + (size_t)gh * W_ + gw] = make_float2(mu, rsqrtf(var + 1e-6f));
        }
    }
}

// =====================================================================
// Kernel B: stage LN2(z)-halo in LDS (bf16, swizzled NHWC) ->
//           dw3 + GELU from LDS -> g_s -> 128x128 pointwise via MFMA
// =====================================================================
__global__ __launch_bounds__(256, 2)
void kernelB(const unsigned short* __restrict__ z, const float2* __restrict__ st2,
             const float* __restrict__ n2w, const float* __restrict__ n2b,
             const float* __restrict__ dwT, const float* __restrict__ dwB,
             const float* __restrict__ pwW, const float* __restrict__ pwB,
             float* __restrict__ out)
{
    __shared__ uint4 w_s4[NHALO_B * 16];                 // 46,080 B
    __shared__ unsigned short g_s[PBH * PBW * GPITCH];   // 34,816 B

    const int tid  = threadIdx.x;
    const int lane = tid & 63;
    const int wv   = tid >> 6;
    const int b    = blockIdx.z;
    const int h0   = blockIdx.y * PBH;
    const int w0   = blockIdx.x * PBW;

    // ---------------- Phase S: stage LN2-normalized halo into w_s4 ----------------
    {
        const int ch = tid & 15;          // 16B chunk (8 channels)
        const int pb = tid >> 4;          // 0..15
        float nw[8], nb[8];
        #pragma unroll
        for (int j = 0; j < 8; ++j) {
            nw[j] = n2w[ch * 8 + j];
            nb[j] = n2b[ch * 8 + j];
        }
        #pragma unroll
        for (int it = 0; it < 12; ++it) {
            const int p = it * 16 + pb;   // halo pixel 0..179
            if (p < NHALO_B) {
                const int ph = p / HBW, pw2 = p - ph * HBW;
                const int gy = h0 - 1 + ph, gx = w0 - 1 + pw2;
                uint4 o = make_uint4(0u, 0u, 0u, 0u);
                if ((unsigned)gy < (unsigned)H_ && (unsigned)gx < (unsigned)W_) {
                    const size_t pp = (size_t)b * HWsz + (size_t)gy * W_ + gx;
                    const uint4 zv = *reinterpret_cast<const uint4*>(z + pp * Cch + ch * 8);
                    const float2 st = st2[pp];
                    const float f0 = (ubf2f((unsigned short)(zv.x & 0xffffu)) - st.x) * st.y * nw[0] + nb[0];
                    const float f1 = (ubf2f((unsigned short)(zv.x >> 16))     - st.x) * st.y * nw[1] + nb[1];
                    const float f2 = (ubf2f((unsigned short)(zv.y & 0xffffu)) - st.x) * st.y * nw[2] + nb[2];
                    const float f3 = (ubf2f((unsigned short)(zv.y >> 16))     - st.x) * st.y * nw[3] + nb[3];
                    const float f4 = (ubf2f((unsigned short)(zv.z & 0xffffu)) - st.x) * st.y * nw[4] + nb[4];
                    const float f5 = (ubf2f((unsigned short)(zv.z >> 16))     - st.x) * st.y * nw[5] + nb[5];
                    const float f6 = (ubf2f((unsigned short)(zv.w & 0xffffu)) - st.x) * st.y * nw[6] + nb[6];
                    const float f7 = (ubf2f((unsigned short)(zv.w >> 16))     - st.x) * st.y * nw[7] + nb[7];
                    o.x = (unsigned)f2ubf(f0) | ((unsigned)f2ubf(f1) << 16);
                    o.y = (unsigned)f2ubf(f2) | ((unsigned)f2ubf(f3) << 16);
                    o.z = (unsigned)f2ubf(f4) | ((unsigned)f2ubf(f5) << 16);
                    o.w = (unsigned)f2ubf(f6) | ((unsigned)f2ubf(f7) << 16);
                }
                w_s4[p * 16 + (ch ^ (p & 15))] = o;
            }
        }
    }
    __syncthreads();

    // ---------------- Phase L: dw3 + GELU from LDS -> g_s (bf16) ----------------
    {
        const int cc = lane & 15;          // channel chunk (8 ch)
        const int sl = lane >> 4;          // 0..3
        const int s  = wv * 4 + sl;        // col in patch 0..15
        const int cbase = cc * 8;

        float db[8];
        float wt[9][8];
        #pragma unroll
        for (int j = 0; j < 8; ++j) db[j] = dwB[cbase + j];
        #pragma unroll
        for (int t = 0; t < 9; ++t)
            #pragma unroll
            for (int j = 0; j < 8; ++j)
                wt[t][j] = dwT[t * Cch + cbase + j];

        for (int r = 0; r < PBH; ++r) {
            float a[8];
            #pragma unroll
            for (int j = 0; j < 8; ++j) a[j] = db[j];

            #pragma unroll
            for (int dy = 0; dy < 3; ++dy)
                #pragma unroll
                for (int dx = 0; dx < 3; ++dx) {
                    const int tap = dy * 3 + dx;
                    const int q = (r + dy) * HBW + (s + dx);
                    const uint4 t4 = w_s4[q * 16 + (cc ^ (q & 15))];
                    a[0] = fmaf(wt[tap][0], ubf2f((unsigned short)(t4.x & 0xffffu)), a[0]);
                    a[1] = fmaf(wt[tap][1], ubf2f((unsigned short)(t4.x >> 16)),     a[1]);
                    a[2] = fmaf(wt[tap][2], ubf2f((unsigned short)(t4.y & 0xffffu)), a[2]);
                    a[3] = fmaf(wt[tap][3], ubf2f((unsigned short)(t4.y >> 16)),     a[3]);
                    a[4] = fmaf(wt[tap][4], ubf2f((unsigned short)(t4.z & 0xffffu)), a[4]);
                    a[5] = fmaf(wt[tap][5], ubf2f((unsigned short)(t4.z >> 16)),     a[5]);
                    a[6] = fmaf(wt[tap][6], ubf2f((unsigned short)(t4.w & 0xffffu)), a[6]);
                    a[7] = fmaf(wt[tap][7], ubf2f((unsigned short)(t4.w >> 16)),     a[7]);
                }

            unsigned int pk[4];
            #pragma unroll
            for (int q = 0; q < 4; ++q) {
                const unsigned short lo = f2ubf(gelu_exact(a[2*q]));
                const unsigned short hi = f2ubf(gelu_exact(a[2*q+1]));
                pk[q] = (unsigned int)lo | ((unsigned int)hi << 16);
            }
            const int row = r * PBW + s;
            const int boff = row * (GPITCH * 2) + ((cbase * 2) ^ ((row & 3) << 4));
            *reinterpret_cast<uint4*>(reinterpret_cast<char*>(g_s) + boff) =
                make_uint4(pk[0], pk[1], pk[2], pk[3]);
        }
    }
    __syncthreads();

    // ---------------- Phase P: 128x128 pointwise via MFMA ----------------
    {
        const int ll = lane & 15;
        const int lh = lane >> 4;

        bf16x8 bfr[2][4];
        float  pb[2];
        #pragma unroll
        for (int t2 = 0; t2 < 2; ++t2) {
            const int o = (wv * 2 + t2) * 16 + ll;
            pb[t2] = pwB[o];
            #pragma unroll
            for (int kt = 0; kt < 4; ++kt) {
                const float* wp = pwW + (size_t)o * Cch + kt * 32 + lh * 8;
                bf16x8 vv;
                #pragma unroll
                for (int j = 0; j < 8; ++j) vv[j] = (__bf16)wp[j];
                bfr[t2][kt] = vv;
            }
        }

        #pragma unroll
        for (int r = 0; r < PBH; ++r) {
            const int row = r * PBW + ll;
            bf16x8 af[4];
            #pragma unroll
            for (int kt = 0; kt < 4; ++kt) {
                const int boff = row * (GPITCH * 2) + ((kt * 64 + lh * 16) ^ ((row & 3) << 4));
                af[kt] = *reinterpret_cast<const bf16x8*>(
                            reinterpret_cast<const char*>(g_s) + boff);
            }
            #pragma unroll
            for (int t2 = 0; t2 < 2; ++t2) {
                f32x4 acc = {0.f, 0.f, 0.f, 0.f};
                #pragma unroll
                for (int kt = 0; kt < 4; ++kt)
                    acc = __builtin_amdgcn_mfma_f32_16x16x32_bf16(af[kt], bfr[t2][kt], acc, 0, 0, 0);
                const int o = (wv * 2 + t2) * 16 + ll;
                float4 res = make_float4(acc[0] + pb[t2], acc[1] + pb[t2],
                                         acc[2] + pb[t2], acc[3] + pb[t2]);
                *reinterpret_cast<float4*>(
                    out + ((size_t)b * Cch + o) * HWsz + (size_t)(h0 + r) * W_ + w0 + lh * 4) = res;
            }
        }
    }
}

// =====================================================================
extern "C" void kernel_launch(void* const* d_in, const int* in_sizes, int n_in,
                              void* d_out, int out_size, void* d_ws, size_t ws_size,
                              hipStream_t stream)
{
    const float* x    = (const float*)d_in[0];
    const float* n1w  = (const float*)d_in[1];
    const float* n1b  = (const float*)d_in[2];
    const float* n2w  = (const float*)d_in[3];
    const float* n2b  = (const float*)d_in[4];
    const float* c5w  = (const float*)d_in[5];
    const float* c5b  = (const float*)d_in[6];
    const float* ldww = (const float*)d_in[7];
    const float* ldwb = (const float*)d_in[8];
    const float* lpww = (const float*)d_in[9];
    const float* lpwb = (const float*)d_in[10];
    const float* s1dw = (const float*)d_in[11];
    const float* s1db = (const float*)d_in[12];
    const float* s1pw = (const float*)d_in[13];
    const float* s1pb = (const float*)d_in[14];
    const float* s2dw = (const float*)d_in[15];
    const float* s2db = (const float*)d_in[16];
    const float* s2pw = (const float*)d_in[17];
    const float* s2pb = (const float*)d_in[18];
    const float* s3dw = (const float*)d_in[19];
    const float* s3db = (const float*)d_in[20];
    const float* s3pw = (const float*)d_in[21];
    const float* s3pb = (const float*)d_in[22];
    const float* s4dw = (const float*)d_in[23];
    const float* s4db = (const float*)d_in[24];
    const float* s4pw = (const float*)d_in[25];
    const float* s4pb = (const float*)d_in[26];

    // workspace layout: y (bf16 NHWC) | z (bf16 NHWC) | st2 (float2) | dwT
    const size_t yBytes  = (size_t)8 * Cch * HWsz * sizeof(unsigned short); // 102,760,448
    const size_t zBytes  = yBytes;                                          // 102,760,448
    const size_t stBytes = (size_t)8 * HWsz * sizeof(float2);               //   3,211,264
    unsigned int*   y_u32 = (unsigned int*)d_ws;
    unsigned short* y_u16 = (unsigned short*)d_ws;
    unsigned int*   z_u32 = (unsigned int*)((char*)d_ws + yBytes);
    unsigned short* z_u16 = (unsigned short*)((char*)d_ws + yBytes);
    float2* st2 = (float2*)((char*)d_ws + yBytes + zBytes);
    float*  dwT = (float*)((char*)d_ws + yBytes + zBytes + stBytes);

    prep<<<dim3(5), 256, 0, stream>>>(ldww, dwT);
    lnT<<<dim3(HWsz / TPX, 8), 256, 0, stream>>>(x, n1w, n1b, y_u32);

    kernelA<<<dim3(W_ / TAW, H_ / TAH, 8), 256, 0, stream>>>(
        y_u16, c5w, c5b,
        s1dw, s1db, s1pw, s1pb,
        s2dw, s2db, s2pw, s2pb,
        s3dw, s3db, s3pw, s3pb,
        s4dw, s4db, s4pw, s4pb, z_u32, st2);

    kernelB<<<dim3(W_ / PBW, H_ / PBH, 8), 256, 0, stream>>>(
        z_u16, st2, n2w, n2b, dwT, ldwb, lpww, lpwb, (float*)d_out);
}